// Round 9
// baseline (1183.104 us; speedup 1.0000x reference)
//
#include <hip/hip_runtime.h>
#include <hip/hip_bf16.h>

#define N_NODES 50000
#define E_EDGES 300000
#define NGRAPH 64
#define NCHUNK 129
#define CPIECE 43    // 129 = 3*43, split-K x3
#define NSTEPP 519   // NCHUNK*4 + 3 pad steps (prefetch distance 3 overrun)
#define NEGRP 1172   // ceil(E/256)
#define LNEPS 1e-5f
#define NBLK_N 196   // ceil(50000/256)
#define NBLK_P 12500 // N_NODES/4
// prescale so RTZ pack to f16 ~= round-to-nearest (adds ~0.5 ulp before trunc)
#define RPRE16 1.00048828125f

typedef _Float16 f16x8 __attribute__((ext_vector_type(8)));
typedef _Float16 f16x2 __attribute__((ext_vector_type(2)));
typedef float floatx4 __attribute__((ext_vector_type(4)));
typedef float f32x2 __attribute__((ext_vector_type(2)));
typedef unsigned int u32x4 __attribute__((ext_vector_type(4)));

// ---------------- prep: Tt2[step][h][kw] f16 via LDS transpose ----------------
// w2 flat index == kf*64 + h (since k*1024+f*64 = 64*kf), so this is a pure
// 32kf x 64h transpose per step-tile; reads and writes both coalesced.
__global__ void k_prep(const float* __restrict__ w2, const float* __restrict__ b2,
                       _Float16* __restrict__ Tt2) {
  __shared__ float tile[32][65];
  int t = threadIdx.x;
  int step = blockIdx.x;          // NSTEPP blocks
  int kf0 = step * 32;
  int kfr = t >> 6;               // 0..3
  int hr = t & 63;
#pragma unroll
  for (int it = 0; it < 8; ++it) {
    int kf = kf0 + it * 4 + kfr;
    float v = 0.f;
    if (kf < 16384) v = w2[(size_t)kf * 64 + hr];
    else if (kf < 16400) v = b2[(size_t)(kf - 16384) * 64 + hr];
    tile[it * 4 + kfr][hr] = v;
  }
  __syncthreads();
  int hw = t >> 2;                // 0..63
  int kw0 = (t & 3) * 8;
  f16x8 pack;
#pragma unroll
  for (int j = 0; j < 8; ++j) pack[j] = (_Float16)tile[kw0 + j][hw];
  *(f16x8*)(Tt2 + (size_t)step * 2048 + hw * 32 + kw0) = pack;
}

__global__ void k_prepw(const float* __restrict__ w1, float* __restrict__ W1t) {
  int i = blockIdx.x * 256 + threadIdx.x;
  if (i < 8192) { int k = i >> 3, j = i & 7; W1t[i] = w1[j * 1024 + k]; }
}

// ---------------- CSR build ----------------
__global__ void k_cnt(const int* __restrict__ ei, int* __restrict__ degI) {
  int e = blockIdx.x * 256 + threadIdx.x;
  if (e < E_EDGES) atomicAdd(&degI[ei[E_EDGES + e]], 1);
}

__global__ void k_scanA(const int* __restrict__ degI, int* __restrict__ bsum) {
  __shared__ int sm[256];
  int t = threadIdx.x;
  int i = blockIdx.x * 256 + t;
  sm[t] = (i < N_NODES) ? degI[i] : 0;
  __syncthreads();
  for (int off = 128; off > 0; off >>= 1) {
    if (t < off) sm[t] += sm[t + off];
    __syncthreads();
  }
  if (t == 0) bsum[blockIdx.x] = sm[0];
}

__global__ void k_scanB(const int* __restrict__ bsum, int* __restrict__ bpre) {
  __shared__ int s[256];
  int t = threadIdx.x;
  int v = (t < NBLK_N) ? bsum[t] : 0;
  s[t] = v;
  __syncthreads();
  for (int off = 1; off < 256; off <<= 1) {
    int add = (t >= off) ? s[t - off] : 0;
    __syncthreads();
    s[t] += add;
    __syncthreads();
  }
  if (t < NBLK_N) bpre[t] = s[t] - v;
}

__global__ void k_scanC(const int* __restrict__ degI, const int* __restrict__ bpre,
                        int* __restrict__ rowptr, int* __restrict__ cursor) {
  __shared__ int s[256];
  int t = threadIdx.x;
  int i = blockIdx.x * 256 + t;
  int d = (i < N_NODES) ? degI[i] : 0;
  s[t] = d;
  __syncthreads();
  for (int off = 1; off < 256; off <<= 1) {
    int add = (t >= off) ? s[t - off] : 0;
    __syncthreads();
    s[t] += add;
    __syncthreads();
  }
  int r = bpre[blockIdx.x] + s[t] - d;   // exclusive
  if (i < N_NODES) {
    rowptr[i] = r;
    cursor[i] = r;
    if (i == N_NODES - 1) rowptr[N_NODES] = r + d;
  }
}

__global__ void k_scatter(const int* __restrict__ ei, int* __restrict__ cursor,
                          int* __restrict__ colsrc) {
  int e = blockIdx.x * 256 + threadIdx.x;
  if (e < E_EDGES) {
    int s = ei[e], d = ei[E_EDGES + e];
    int pos = atomicAdd(&cursor[d], 1);
    colsrc[pos] = s;
  }
}

// ---------------- NNConv fused MFMA GEMM, split-K x3, register-direct B (f16) ----------------
// R9: (1) split-K x3 -> 3516 blocks: 5 lockstep rounds @91.6% vs 4 @76% (tail fix);
// (2) chunk body reordered extract->r-pipeline(c+1)->MFMA so the ~450cyc SMEM+bpermute
// r-chain is covered by the ~1242cyc MFMA phase; (3) B prefetch distance 3.
// ZERO LDS, ZERO barriers. min-waves 3 (R3: (256,4) spills acc).
__global__ __launch_bounds__(256, 3)
void k_nnconv(const float* __restrict__ x, const int* __restrict__ ei,
              const float* __restrict__ ea, const float* __restrict__ W1t,
              const float* __restrict__ b1, const _Float16* __restrict__ Tt2,
              float* __restrict__ agg) {
  const int tid = threadIdx.x;
  const int lane = tid & 63;
  const int l15 = lane & 15;
  const int quad = lane >> 4;
  const bool qhi = (lane & 32) != 0;     // k_local = quad>>1: selects which r of the pair
  // splat selector: replicate chosen 16-bit half of ubuf into both halves
  const unsigned rsel = qhi ? 0x07060706u : 0x05040504u;
  const int piece = blockIdx.x / NEGRP;  // 0..2
  const int grp = blockIdx.x - piece * NEGRP;
  const int cstart = piece * CPIECE;
  const int cend = cstart + CPIECE;

  int e = grp * 256 + tid;
  bool valid = e < E_EDGES;
  int srcv = valid ? ei[e] : 0;
  int dstv = valid ? ei[E_EDGES + e] : -1;

  f32x2 ea2[4];
  {
    const float4* p = (const float4*)(ea + (size_t)(valid ? e : 0) * 8);
    float4 a0 = p[0], a1 = p[1];
    ea2[0] = (f32x2){a0.x, a0.y};
    ea2[1] = (f32x2){a0.z, a0.w};
    ea2[2] = (f32x2){a1.x, a1.y};
    ea2[3] = (f32x2){a1.z, a1.w};
  }

  // persistent x fragments packed to f16 pairs (4 regs per mb)
  const int f0 = (quad & 1) * 8;
  unsigned xh16[4][4];
#pragma unroll
  for (int mb = 0; mb < 4; ++mb) {
    int s = __shfl(srcv, mb * 16 + l15);
    const float4* px = (const float4*)(x + (size_t)s * 16 + f0);
    float4 v0 = px[0], v1 = px[1];
    xh16[mb][0] = __builtin_bit_cast(unsigned, __builtin_amdgcn_cvt_pkrtz(v0.x * RPRE16, v0.y * RPRE16));
    xh16[mb][1] = __builtin_bit_cast(unsigned, __builtin_amdgcn_cvt_pkrtz(v0.z * RPRE16, v0.w * RPRE16));
    xh16[mb][2] = __builtin_bit_cast(unsigned, __builtin_amdgcn_cvt_pkrtz(v1.x * RPRE16, v1.y * RPRE16));
    xh16[mb][3] = __builtin_bit_cast(unsigned, __builtin_amdgcn_cvt_pkrtz(v1.z * RPRE16, v1.w * RPRE16));
  }

  // bpermute byte addresses for r broadcast (lane mb*16+l15)
  int bpaddr[4];
#pragma unroll
  for (int mb = 0; mb < 4; ++mb) bpaddr[mb] = (mb * 16 + l15) * 4;

  // B stream pointer: per-lane offset inside a [64h][32kw] step-tile
  const _Float16* bp = Tt2 + (size_t)(cstart * 4) * 2048 + (l15 * 32 + quad * 8);

  f16x8 Bq[4][4];
  auto loadB = [&](int which) {
    Bq[which][0] = *(const f16x8*)(bp);
    Bq[which][1] = *(const f16x8*)(bp + 512);
    Bq[which][2] = *(const f16x8*)(bp + 1024);
    Bq[which][3] = *(const f16x8*)(bp + 1536);
    bp += 2048;
  };

  unsigned prr[4];   // f16-packed r pair per k-step: lo16=r[2ks], hi16=r[2ks+1]
  auto calcR = [&](int c, const float* w1p, const float* b1p) {
    if (c < 128) {   // uniform branch
#pragma unroll
      for (int ks = 0; ks < 4; ++ks) {
        float rv[2];
#pragma unroll
        for (int kk = 0; kk < 2; ++kk) {
          const f32x2* w = (const f32x2*)(w1p + (ks * 2 + kk) * 8);  // uniform -> s_load
          f32x2 s01 = ea2[0] * w[0] + ea2[1] * w[1];
          f32x2 s23 = ea2[2] * w[2] + ea2[3] * w[3];
          f32x2 s = s01 + s23;
          rv[kk] = fmaxf(b1p[ks * 2 + kk] + s[0] + s[1], 0.f) * RPRE16;
        }
        prr[ks] = __builtin_bit_cast(unsigned, __builtin_amdgcn_cvt_pkrtz(rv[0], rv[1]));
      }
    } else {
      prr[0] = 0x00003C00u;  // lo16 = f16(1.0) at k=1024 (b2 rows); rest 0
      prr[1] = prr[2] = prr[3] = 0u;
    }
  };

  unsigned ubuf[16]; // bpermuted r pairs for the CURRENT chunk, [ks*4+mb]
  auto bcastR = [&]() {
#pragma unroll
    for (int ks = 0; ks < 4; ++ks)
#pragma unroll
      for (int mb = 0; mb < 4; ++mb)
        ubuf[ks * 4 + mb] = (unsigned)__builtin_amdgcn_ds_bpermute(bpaddr[mb], (int)prr[ks]);
  };

  floatx4 acc[4][4];
#pragma unroll
  for (int mb = 0; mb < 4; ++mb)
#pragma unroll
    for (int nb = 0; nb < 4; ++nb) acc[mb][nb] = floatx4{0.f, 0.f, 0.f, 0.f};

  calcR(cstart, W1t + cstart * 64, b1 + cstart * 8);
  bcastR();
  loadB(0);
  loadB(1);
  loadB(2);
  const float* w1p = W1t + (cstart + 1) * 64;
  const float* b1p = b1 + (cstart + 1) * 8;

  for (int c = cstart; c < cend; ++c) {
    // 1) extract this chunk's splatted r pairs (frees ubuf for rewrite)
    unsigned rsp[16];
#pragma unroll
    for (int i = 0; i < 16; ++i)
      rsp[i] = __builtin_amdgcn_perm(ubuf[i], 0u, rsel);
    // 2) launch next chunk's r pipeline NOW -> its SMEM+bpermute latency is
    //    covered by this chunk's MFMA phase below
    if (c + 1 < cend) {
      calcR(c + 1, w1p, b1p);
      bcastR();
      w1p += 64; b1p += 8;
    }
    // 3) MFMA phase
#pragma unroll
    for (int ks = 0; ks < 4; ++ks) {
      loadB((ks + 3) & 3);   // prefetch 3 steps ahead (tail reads zero-pad steps)
#pragma unroll
      for (int mb = 0; mb < 4; ++mb) {
        f16x2 r2 = __builtin_bit_cast(f16x2, rsp[ks * 4 + mb]);
        u32x4 U;
#pragma unroll
        for (int j = 0; j < 4; ++j)
          U[j] = __builtin_bit_cast(unsigned,
                   __builtin_bit_cast(f16x2, xh16[mb][j]) * r2);
        f16x8 A = __builtin_bit_cast(f16x8, U);
#pragma unroll
        for (int nb = 0; nb < 4; ++nb)
          acc[mb][nb] = __builtin_amdgcn_mfma_f32_16x16x32_f16(A, Bq[ks][nb], acc[mb][nb], 0, 0, 0);
      }
    }
  }

  // epilogue: scatter partial msg to agg[dst]  (C layout: row=quad*4+reg, col=l15)
#pragma unroll
  for (int mb = 0; mb < 4; ++mb) {
#pragma unroll
    for (int reg = 0; reg < 4; ++reg) {
      int dd = __shfl(dstv, mb * 16 + quad * 4 + reg);
      if (dd >= 0) {
#pragma unroll
        for (int nb = 0; nb < 4; ++nb)
          atomicAdd(&agg[(size_t)dd * 64 + nb * 16 + l15], acc[mb][nb][reg]);
      }
    }
  }
}

// ---------------- h = relu(x@rootw + agg/deg + b); LN1 partials ----------------
__global__ void k_root(const float* __restrict__ x, const float* __restrict__ rootw,
                       const float* __restrict__ conv1b, const float* __restrict__ agg,
                       const int* __restrict__ degI, float* __restrict__ hpre,
                       float* __restrict__ rpart) {
  __shared__ float sW[1024];
  __shared__ float sx[64];
  __shared__ float red[8];
  int t = threadIdx.x;
  int blk = blockIdx.x;
#pragma unroll
  for (int i = 0; i < 4; ++i) sW[t + i * 256] = rootw[t + i * 256];
  if (t < 64) sx[t] = x[(size_t)blk * 64 + t];
  __syncthreads();
  int ln = t >> 6, h = t & 63;
  int n = blk * 4 + ln;
  float acc = conv1b[h];
#pragma unroll
  for (int f = 0; f < 16; ++f) acc += sx[ln * 16 + f] * sW[f * 64 + h];
  float dv = fmaxf((float)degI[n], 1.0f);
  float v = acc + agg[(size_t)n * 64 + h] / dv;
  v = fmaxf(v, 0.f);
  hpre[(size_t)n * 64 + h] = v;
  float s1 = v, s2 = v * v;
  for (int o = 32; o > 0; o >>= 1) { s1 += __shfl_down(s1, o); s2 += __shfl_down(s2, o); }
  if ((t & 63) == 0) { red[t >> 6] = s1; red[4 + (t >> 6)] = s2; }
  __syncthreads();
  if (t == 0) {
    rpart[blk * 2] = red[0] + red[1] + red[2] + red[3];
    rpart[blk * 2 + 1] = red[4] + red[5] + red[6] + red[7];
  }
}

// reduce LN1 partials; fold LN1 into gat_w
__global__ void k_fold1(const float* __restrict__ rpart, const float* __restrict__ n1w,
                        const float* __restrict__ n1b, const float* __restrict__ gatw,
                        float* __restrict__ gw2, float* __restrict__ tb) {
  __shared__ float red[8];
  __shared__ float sMI[2];
  __shared__ float sS[64], sT[64];
  int t = threadIdx.x;
  int wv = t >> 6, lane = t & 63;
  float a = 0.f, b = 0.f;
  for (int i = t; i < NBLK_P; i += 256) { a += rpart[2 * i]; b += rpart[2 * i + 1]; }
  for (int o = 32; o > 0; o >>= 1) { a += __shfl_down(a, o); b += __shfl_down(b, o); }
  if (lane == 0) { red[wv] = a; red[4 + wv] = b; }
  __syncthreads();
  if (t == 0) {
    float A = red[0] + red[1] + red[2] + red[3];
    float B = red[4] + red[5] + red[6] + red[7];
    const float M = (float)N_NODES * 64.f;
    float mu = A / M;
    float var = fmaxf(B / M - mu * mu, 0.f);
    sMI[0] = mu;
    sMI[1] = 1.f / (sqrtf(var) + LNEPS);
  }
  __syncthreads();
  if (t < 64) {
    float mu = sMI[0], inv = sMI[1];
    sS[t] = inv * n1w[t];
    sT[t] = n1b[t] - mu * inv * n1w[t];
  }
  __syncthreads();
  if (t < 64) {
    float acc = 0.f;
    for (int i = 0; i < 64; ++i) {
      float g = gatw[i * 64 + t];
      gw2[i * 64 + t] = sS[i] * g;
      acc += sT[i] * g;
    }
    tb[t] = acc;
  }
}

// xh = hpre@gw2 + tb ; attention scalars
__global__ void k_gatlin(const float* __restrict__ hpre, const float* __restrict__ gw2,
                         const float* __restrict__ tb, const float* __restrict__ attS,
                         const float* __restrict__ attD, float* __restrict__ xh,
                         float* __restrict__ asrc, float* __restrict__ adst) {
  __shared__ float sW[4096];
  __shared__ float sh[256];
  __shared__ float sxh[256];
  int t = threadIdx.x;
  int blk = blockIdx.x;
#pragma unroll
  for (int i = 0; i < 16; ++i) sW[t + i * 256] = gw2[t + i * 256];
  sh[t] = hpre[(size_t)blk * 256 + t];
  __syncthreads();
  int ln = t >> 6, h = t & 63;
  float acc = tb[h];
  for (int i = 0; i < 64; ++i) acc += sh[ln * 64 + i] * sW[i * 64 + h];
  xh[(size_t)blk * 256 + t] = acc;
  sxh[t] = acc;
  __syncthreads();
  if (t < 32) {
    int ln2 = t >> 3, rem = t & 7;
    int hd = rem & 3;
    const float* av = (rem >> 2) ? attD : attS;
    float a = 0.f;
#pragma unroll
    for (int d = 0; d < 16; ++d) a += sxh[ln2 * 64 + hd * 16 + d] * av[hd * 16 + d];
    int n = blk * 4 + ln2;
    if (rem >> 2) adst[n * 4 + hd] = a; else asrc[n * 4 + hd] = a;
  }
}

// ---------------- GAT: CSR gather, online softmax, fused relu + LN2 partials ----------------
__global__ void k_gat(const int* __restrict__ rowptr, const int* __restrict__ colsrc,
                      const float* __restrict__ xh, const float* __restrict__ asrc,
                      const float* __restrict__ adst, const float* __restrict__ gatb,
                      float* __restrict__ act, float* __restrict__ gpart) {
  __shared__ float sP[4][256];
  __shared__ int sS[4][64];
  __shared__ float sRed[8];
  int t = threadIdx.x;
  int wv = t >> 6, lane = t & 63;
  int n = blockIdx.x * 4 + wv;
  int start = rowptr[n], end = rowptr[n + 1];
  int deg = end - start;
  int myhd = lane >> 4;
  float ad[4];
#pragma unroll
  for (int hd = 0; hd < 4; ++hd) ad[hd] = adst[n * 4 + hd];
  float m[4] = {-1e30f, -1e30f, -1e30f, -1e30f};
  float l[4] = {0.f, 0.f, 0.f, 0.f};
  float O = 0.f;
  int items = deg + 1;  // + self loop
  for (int t0 = 0; t0 < items; t0 += 64) {
    int cnt = min(64, items - t0);
    int idx = t0 + lane;
    bool has = lane < cnt;
    int s = n;
    if (has && idx < deg) s = colsrc[start + idx];
    float a[4];
#pragma unroll
    for (int hd = 0; hd < 4; ++hd) {
      float av = has ? (asrc[s * 4 + hd] + ad[hd]) : -1e30f;
      a[hd] = (av > 0.f) ? av : 0.2f * av;  // leaky relu 0.2
    }
    float tm[4];
#pragma unroll
    for (int hd = 0; hd < 4; ++hd) tm[hd] = a[hd];
#pragma unroll
    for (int off = 32; off > 0; off >>= 1)
#pragma unroll
      for (int hd = 0; hd < 4; ++hd) tm[hd] = fmaxf(tm[hd], __shfl_xor(tm[hd], off));
    float p[4];
#pragma unroll
    for (int hd = 0; hd < 4; ++hd) {
      float mn = fmaxf(m[hd], tm[hd]);
      float sc = __expf(m[hd] - mn);
      l[hd] *= sc;
      if (hd == myhd) O *= sc;
      m[hd] = mn;
      p[hd] = has ? __expf(a[hd] - mn) : 0.f;
    }
    float ts[4];
#pragma unroll
    for (int hd = 0; hd < 4; ++hd) ts[hd] = p[hd];
#pragma unroll
    for (int off = 32; off > 0; off >>= 1)
#pragma unroll
      for (int hd = 0; hd < 4; ++hd) ts[hd] += __shfl_xor(ts[hd], off);
#pragma unroll
    for (int hd = 0; hd < 4; ++hd) l[hd] += ts[hd];
    sS[wv][lane] = s;
#pragma unroll
    for (int hd = 0; hd < 4; ++hd) sP[wv][lane * 4 + hd] = p[hd];
    // wave-private LDS region: program order suffices, no barrier
    for (int e2 = 0; e2 < cnt; ++e2) {
      int ss = sS[wv][e2];
      float pp = sP[wv][e2 * 4 + myhd];
      O = fmaf(pp, xh[(size_t)ss * 64 + lane], O);
    }
  }
  float lmy = (myhd & 2) ? ((myhd & 1) ? l[3] : l[2]) : ((myhd & 1) ? l[1] : l[0]);
  float outv = O / (lmy + 1e-16f);
  float v = fmaxf(outv + gatb[lane], 0.f);
  act[(size_t)n * 64 + lane] = v;
  float s1 = v, s2 = v * v;
#pragma unroll
  for (int off = 32; off > 0; off >>= 1) { s1 += __shfl_down(s1, off); s2 += __shfl_down(s2, off); }
  if (lane == 0) { sRed[wv] = s1; sRed[4 + wv] = s2; }
  __syncthreads();
  if (t == 0) {
    gpart[blockIdx.x * 2] = sRed[0] + sRed[1] + sRed[2] + sRed[3];
    gpart[blockIdx.x * 2 + 1] = sRed[4] + sRed[5] + sRed[6] + sRed[7];
  }
}

// reduce LN2 partials; fold LN2 + linear head into wl
__global__ void k_fold2(const float* __restrict__ gpart, const float* __restrict__ n2w,
                        const float* __restrict__ n2b, const float* __restrict__ linw,
                        const float* __restrict__ linb, float* __restrict__ wl) {
  __shared__ float red[8];
  __shared__ float sMI[2];
  int t = threadIdx.x;
  int wv = t >> 6, lane = t & 63;
  float a = 0.f, b = 0.f;
  for (int i = t; i < NBLK_P; i += 256) { a += gpart[2 * i]; b += gpart[2 * i + 1]; }
  for (int o = 32; o > 0; o >>= 1) { a += __shfl_down(a, o); b += __shfl_down(b, o); }
  if (lane == 0) { red[wv] = a; red[4 + wv] = b; }
  __syncthreads();
  if (t == 0) {
    float A = red[0] + red[1] + red[2] + red[3];
    float B = red[4] + red[5] + red[6] + red[7];
    const float M = (float)N_NODES * 64.f;
    float mu = A / M;
    float var = fmaxf(B / M - mu * mu, 0.f);
    sMI[0] = mu;
    sMI[1] = 1.f / (sqrtf(var) + LNEPS);
  }
  __syncthreads();
  if (t < 64) {
    float mu = sMI[0], inv = sMI[1];
    float w = inv * n2w[t] * linw[t];
    float p = (n2b[t] - mu * inv * n2w[t]) * linw[t];
    wl[t] = w;
    for (int o = 32; o > 0; o >>= 1) p += __shfl_down(p, o);
    if (t == 0) wl[64] = p + linb[0];
  }
}

// per-graph segmented pool + head (batch is sorted; zero atomics)
__global__ void k_out(const float* __restrict__ act, const float* __restrict__ wl,
                      const int* __restrict__ batch, float* __restrict__ out) {
  __shared__ float red[4];
  __shared__ float swl[64];
  int g = blockIdx.x;
  int t = threadIdx.x;
  int wv = t >> 6, lane = t & 63;
  if (t < 64) swl[t] = wl[t];
  __syncthreads();
  auto lbound = [&](int key) {
    int lo = 0, hi = N_NODES;
    while (lo < hi) { int mid = (lo + hi) >> 1; if (batch[mid] < key) lo = mid + 1; else hi = mid; }
    return lo;
  };
  int lo = lbound(g), hi = lbound(g + 1);
  int cntn = hi - lo;
  float s = 0.f;
  for (int idx = t; idx < cntn * 64; idx += 256) {
    int n = lo + (idx >> 6);
    int d = idx & 63;
    s += act[(size_t)n * 64 + d] * swl[d];
  }
  for (int o = 32; o > 0; o >>= 1) s += __shfl_down(s, o);
  if (lane == 0) red[wv] = s;
  __syncthreads();
  if (t == 0)
    out[g] = (red[0] + red[1] + red[2] + red[3]) / fmaxf((float)cntn, 1.f) + wl[64];
}

// ---------------- workspace layout (bytes, 64B aligned) ----------------
#define OFF_AGG     0UL
#define OFF_DEGI    12800000UL
#define ZBYTES      13000000UL
#define OFF_RPART   13000000UL
#define OFF_GPART   13100032UL
#define OFF_ROWPTR  13200064UL
#define OFF_CURSOR  13400128UL
#define OFF_BSUM    13600192UL
#define OFF_BPRE    13601024UL
#define OFF_COLSRC  13601856UL
#define OFF_TT      14801856UL   // NSTEPP*2048*2 = 2125824 (incl. 3 zero pad steps)
#define OFF_W1T     16927680UL
#define OFF_GW2     16960448UL
#define OFF_TB      16976832UL
#define OFF_WL      16977088UL
#define OFF_ASRC    16977408UL
#define OFF_ADST    17777408UL
#define OFF_HPRE    18577408UL
#define OFF_XH      31377408UL
#define OFF_ACT     44177408UL
#define WS_NEED     56977408UL

extern "C" void kernel_launch(void* const* d_in, const int* in_sizes, int n_in,
                              void* d_out, int out_size, void* d_ws, size_t ws_size,
                              hipStream_t stream) {
  const float* x = (const float*)d_in[0];
  const int* ei = (const int*)d_in[1];
  const float* ea = (const float*)d_in[2];
  const int* batch = (const int*)d_in[3];
  const float* w1 = (const float*)d_in[4];
  const float* b1 = (const float*)d_in[5];
  const float* w2 = (const float*)d_in[6];
  const float* b2 = (const float*)d_in[7];
  const float* rootw = (const float*)d_in[8];
  const float* conv1b = (const float*)d_in[9];
  const float* n1w = (const float*)d_in[10];
  const float* n1b = (const float*)d_in[11];
  const float* gatw = (const float*)d_in[12];
  const float* attS = (const float*)d_in[13];
  const float* attD = (const float*)d_in[14];
  const float* gatb = (const float*)d_in[15];
  const float* n2w = (const float*)d_in[16];
  const float* n2b = (const float*)d_in[17];
  const float* linw = (const float*)d_in[18];
  const float* linb = (const float*)d_in[19];

  if (ws_size < WS_NEED) return;
  char* ws = (char*)d_ws;
  float* agg    = (float*)(ws + OFF_AGG);
  int* degI     = (int*)(ws + OFF_DEGI);
  float* rpart  = (float*)(ws + OFF_RPART);
  float* gpart  = (float*)(ws + OFF_GPART);
  int* rowptr   = (int*)(ws + OFF_ROWPTR);
  int* cursor   = (int*)(ws + OFF_CURSOR);
  int* bsum     = (int*)(ws + OFF_BSUM);
  int* bpre     = (int*)(ws + OFF_BPRE);
  int* colsrc   = (int*)(ws + OFF_COLSRC);
  _Float16* Tt2 = (_Float16*)(ws + OFF_TT);
  float* W1t    = (float*)(ws + OFF_W1T);
  float* gw2    = (float*)(ws + OFF_GW2);
  float* tb     = (float*)(ws + OFF_TB);
  float* wl     = (float*)(ws + OFF_WL);
  float* asrc   = (float*)(ws + OFF_ASRC);
  float* adst   = (float*)(ws + OFF_ADST);
  float* hpre   = (float*)(ws + OFF_HPRE);
  float* xh     = (float*)(ws + OFF_XH);
  float* act    = (float*)(ws + OFF_ACT);

  hipMemsetAsync(ws, 0, ZBYTES, stream);

  k_prep<<<NSTEPP, 256, 0, stream>>>(w2, b2, Tt2);
  k_prepw<<<32, 256, 0, stream>>>(w1, W1t);
  k_cnt<<<(E_EDGES + 255) / 256, 256, 0, stream>>>(ei, degI);
  k_scanA<<<NBLK_N, 256, 0, stream>>>(degI, bsum);
  k_scanB<<<1, 256, 0, stream>>>(bsum, bpre);
  k_scanC<<<NBLK_N, 256, 0, stream>>>(degI, bpre, rowptr, cursor);
  k_scatter<<<(E_EDGES + 255) / 256, 256, 0, stream>>>(ei, cursor, colsrc);
  k_nnconv<<<NEGRP * 3, 256, 0, stream>>>(x, ei, ea, W1t, b1, Tt2, agg);
  k_root<<<NBLK_P, 256, 0, stream>>>(x, rootw, conv1b, agg, degI, hpre, rpart);
  k_fold1<<<1, 256, 0, stream>>>(rpart, n1w, n1b, gatw, gw2, tb);
  k_gatlin<<<NBLK_P, 256, 0, stream>>>(hpre, gw2, tb, attS, attD, xh, asrc, adst);
  k_gat<<<NBLK_P, 256, 0, stream>>>(rowptr, colsrc, xh, asrc, adst, gatb, act, gpart);
  k_fold2<<<1, 256, 0, stream>>>(gpart, n2w, n2b, linw, linb, wl);
  k_out<<<NGRAPH, 256, 0, stream>>>(act, wl, batch, (float*)d_out);
}

// Round 10
// 1004.821 us; speedup vs baseline: 1.1774x; 1.1774x over previous
//
#include <hip/hip_runtime.h>
#include <hip/hip_bf16.h>

#define N_NODES 50000
#define E_EDGES 300000
#define NGRAPH 64
#define NCHUNK 129
#define CSPLIT 65    // piece 0: c in [0,65), piece 1: [65,129)
#define NKG 1034     // 129*8 kgroups + 2 pad (prefetch distance 2 overrun)
#define NEGRP 1172   // ceil(E/256)
#define LNEPS 1e-5f
#define NBLK_N 196   // ceil(50000/256)
#define NBLK_P 12500 // N_NODES/4
// prescale so RTZ pack to f16 ~= round-to-nearest
#define RPRE16 1.00048828125f

typedef _Float16 f16x8 __attribute__((ext_vector_type(8)));
typedef _Float16 f16x2 __attribute__((ext_vector_type(2)));
typedef float floatx16 __attribute__((ext_vector_type(16)));
typedef float f32x2 __attribute__((ext_vector_type(2)));
typedef unsigned int u32x4 __attribute__((ext_vector_type(4)));

// ---------------- prep: Tt3[kg][half][n][j] f16 ----------------
// element (kg, half, n, j) = T[kf = kg*16 + half*8 + j][n]; per-kg tile = 1024 f16 (2 KB).
// B-lane (n=lane&31, k=(lane>>5)*8+j) then reads 16B fully coalesced.
__global__ void k_prep(const float* __restrict__ w2, const float* __restrict__ b2,
                       _Float16* __restrict__ Tt3) {
  int idx = blockIdx.x * 256 + threadIdx.x;   // NKG*1024 elements
  int kg = idx >> 10;
  int o = idx & 1023;
  int half = o >> 9;
  int n = (o >> 3) & 63;
  int j = o & 7;
  int kf = kg * 16 + half * 8 + j;
  float v = 0.f;
  if (kf < 16384) v = w2[(size_t)kf * 64 + n];        // w2 flat = kf*64+h
  else if (kf < 16400) v = b2[(size_t)(kf - 16384) * 64 + n];
  Tt3[idx] = (_Float16)v;
}

__global__ void k_prepw(const float* __restrict__ w1, float* __restrict__ W1t) {
  int i = blockIdx.x * 256 + threadIdx.x;
  if (i < 8192) { int k = i >> 3, j = i & 7; W1t[i] = w1[j * 1024 + k]; }
}

// ---------------- CSR build ----------------
__global__ void k_cnt(const int* __restrict__ ei, int* __restrict__ degI) {
  int e = blockIdx.x * 256 + threadIdx.x;
  if (e < E_EDGES) atomicAdd(&degI[ei[E_EDGES + e]], 1);
}

__global__ void k_scanA(const int* __restrict__ degI, int* __restrict__ bsum) {
  __shared__ int sm[256];
  int t = threadIdx.x;
  int i = blockIdx.x * 256 + t;
  sm[t] = (i < N_NODES) ? degI[i] : 0;
  __syncthreads();
  for (int off = 128; off > 0; off >>= 1) {
    if (t < off) sm[t] += sm[t + off];
    __syncthreads();
  }
  if (t == 0) bsum[blockIdx.x] = sm[0];
}

__global__ void k_scanB(const int* __restrict__ bsum, int* __restrict__ bpre) {
  __shared__ int s[256];
  int t = threadIdx.x;
  int v = (t < NBLK_N) ? bsum[t] : 0;
  s[t] = v;
  __syncthreads();
  for (int off = 1; off < 256; off <<= 1) {
    int add = (t >= off) ? s[t - off] : 0;
    __syncthreads();
    s[t] += add;
    __syncthreads();
  }
  if (t < NBLK_N) bpre[t] = s[t] - v;
}

__global__ void k_scanC(const int* __restrict__ degI, const int* __restrict__ bpre,
                        int* __restrict__ rowptr, int* __restrict__ cursor) {
  __shared__ int s[256];
  int t = threadIdx.x;
  int i = blockIdx.x * 256 + t;
  int d = (i < N_NODES) ? degI[i] : 0;
  s[t] = d;
  __syncthreads();
  for (int off = 1; off < 256; off <<= 1) {
    int add = (t >= off) ? s[t - off] : 0;
    __syncthreads();
    s[t] += add;
    __syncthreads();
  }
  int r = bpre[blockIdx.x] + s[t] - d;   // exclusive
  if (i < N_NODES) {
    rowptr[i] = r;
    cursor[i] = r;
    if (i == N_NODES - 1) rowptr[N_NODES] = r + d;
  }
}

__global__ void k_scatter(const int* __restrict__ ei, int* __restrict__ cursor,
                          int* __restrict__ colsrc) {
  int e = blockIdx.x * 256 + threadIdx.x;
  if (e < E_EDGES) {
    int s = ei[e], d = ei[E_EDGES + e];
    int pos = atomicAdd(&cursor[d], 1);
    colsrc[pos] = s;
  }
}

// ---------------- NNConv fused MFMA GEMM, split-K x2, 32x32x16 f16 ----------------
// R10: (1) 32x32x16 f16 MFMA (higher ceiling 2178 TF, half the MFMA instrs & bpermutes);
// (2) R9-reorder: extract -> calcR+bcastR(c+1) -> MFMA phase, so the r-chain latency is
// covered by the MFMA phase instead of the loop back-edge; (3) split-K x2 (R9: x3 regressed).
// ZERO LDS, ZERO barriers. min-waves 3 (R3: (256,4) spills acc).
// Layouts: A[m][k]: m=lane&31, k=(lane>>5)*8+j. B[k][n]: n=lane&31, k=(lane>>5)*8+j.
// C/D: col=lane&31, row=(reg&3)+8*(reg>>2)+4*(lane>>5)  [m74/m101 verified].
__global__ __launch_bounds__(256, 3)
void k_nnconv(const float* __restrict__ x, const int* __restrict__ ei,
              const float* __restrict__ ea, const float* __restrict__ W1t,
              const float* __restrict__ b1, const _Float16* __restrict__ Tt3,
              float* __restrict__ agg) {
  const int tid = threadIdx.x;
  const int lane = tid & 63;
  const int l31 = lane & 31;
  const int half = lane >> 5;
  const int grp = blockIdx.x >> 1;
  const int piece = blockIdx.x & 1;
  const int cstart = piece ? CSPLIT : 0;
  const int cend = piece ? NCHUNK : CSPLIT;

  int e = grp * 256 + tid;
  bool valid = e < E_EDGES;
  int srcv = valid ? ei[e] : 0;
  int dstv = valid ? ei[E_EDGES + e] : -1;

  f32x2 ea2[4];
  {
    const float4* p = (const float4*)(ea + (size_t)(valid ? e : 0) * 8);
    float4 a0 = p[0], a1 = p[1];
    ea2[0] = (f32x2){a0.x, a0.y};
    ea2[1] = (f32x2){a0.z, a0.w};
    ea2[2] = (f32x2){a1.x, a1.y};
    ea2[3] = (f32x2){a1.z, a1.w};
  }

  // persistent x fragments: mt in {0,1}, edge m = mt*32+l31, f = half*8 + j
  const int f0 = half * 8;
  unsigned xh16[2][4];
#pragma unroll
  for (int mt = 0; mt < 2; ++mt) {
    int s = __shfl(srcv, mt * 32 + l31);
    const float4* px = (const float4*)(x + (size_t)s * 16 + f0);
    float4 v0 = px[0], v1 = px[1];
    xh16[mt][0] = __builtin_bit_cast(unsigned, __builtin_amdgcn_cvt_pkrtz(v0.x * RPRE16, v0.y * RPRE16));
    xh16[mt][1] = __builtin_bit_cast(unsigned, __builtin_amdgcn_cvt_pkrtz(v0.z * RPRE16, v0.w * RPRE16));
    xh16[mt][2] = __builtin_bit_cast(unsigned, __builtin_amdgcn_cvt_pkrtz(v1.x * RPRE16, v1.y * RPRE16));
    xh16[mt][3] = __builtin_bit_cast(unsigned, __builtin_amdgcn_cvt_pkrtz(v1.z * RPRE16, v1.w * RPRE16));
  }

  // bpermute byte addresses: lane wants r of edge (mt*32 + l31)
  int bpaddr[2];
#pragma unroll
  for (int mt = 0; mt < 2; ++mt) bpaddr[mt] = (mt * 32 + l31) * 4;

  // B stream: uniform base (advances 1024 elems/kg) + fixed lane offset
  const _Float16* sb = Tt3 + (size_t)(cstart * 8) * 1024;
  const int loff = half * 512 + l31 * 8;   // elements

  f16x8 Bs[4][2];   // 4 slots x 2 ntiles x 4 regs = 32 VGPRs
  auto loadB = [&](int slot) {
    Bs[slot][0] = *(const f16x8*)(sb + loff);
    Bs[slot][1] = *(const f16x8*)(sb + loff + 256);  // ntile 1: n += 32 -> +32*8 elems
    sb += 1024;
  };

  unsigned prr[4];   // f16-packed r pair: lo16=r[2p], hi16=r[2p+1]
  auto calcR = [&](int c, const float* w1p, const float* b1p) {
    if (c < 128) {   // uniform branch
#pragma unroll
      for (int p = 0; p < 4; ++p) {
        float rv[2];
#pragma unroll
        for (int kk = 0; kk < 2; ++kk) {
          const f32x2* w = (const f32x2*)(w1p + (p * 2 + kk) * 8);  // uniform -> s_load
          f32x2 s01 = ea2[0] * w[0] + ea2[1] * w[1];
          f32x2 s23 = ea2[2] * w[2] + ea2[3] * w[3];
          f32x2 s = s01 + s23;
          rv[kk] = fmaxf(b1p[p * 2 + kk] + s[0] + s[1], 0.f) * RPRE16;
        }
        prr[p] = __builtin_bit_cast(unsigned, __builtin_amdgcn_cvt_pkrtz(rv[0], rv[1]));
      }
    } else {
      prr[0] = 0x00003C00u;  // lo16 = f16(1.0) at k=1024 (b2 rows); rest 0
      prr[1] = prr[2] = prr[3] = 0u;
    }
  };

  unsigned ubuf[8]; // bpermuted r pairs for CURRENT chunk: [pair*2 + mt]
  auto bcastR = [&]() {
#pragma unroll
    for (int p = 0; p < 4; ++p)
#pragma unroll
      for (int mt = 0; mt < 2; ++mt)
        ubuf[p * 2 + mt] = (unsigned)__builtin_amdgcn_ds_bpermute(bpaddr[mt], (int)prr[p]);
  };

  floatx16 acc[2][2];
#pragma unroll
  for (int mt = 0; mt < 2; ++mt)
#pragma unroll
    for (int nt = 0; nt < 2; ++nt)
#pragma unroll
      for (int r = 0; r < 16; ++r) acc[mt][nt][r] = 0.f;

  calcR(cstart, W1t + cstart * 64, b1 + cstart * 8);
  bcastR();
  loadB(0);
  loadB(1);
  const float* w1p = W1t + (cstart + 1) * 64;
  const float* b1p = b1 + (cstart + 1) * 8;

  for (int c = cstart; c < cend; ++c) {
    // 1) extract all splatted r values for this chunk (kg 0..7 x mt)
    unsigned rsp[16];
#pragma unroll
    for (int p = 0; p < 4; ++p)
#pragma unroll
      for (int mt = 0; mt < 2; ++mt) {
        unsigned u = ubuf[p * 2 + mt];
        rsp[(2 * p) * 2 + mt]     = __builtin_amdgcn_perm(u, 0u, 0x05040504u); // lo half
        rsp[(2 * p + 1) * 2 + mt] = __builtin_amdgcn_perm(u, 0u, 0x07060706u); // hi half
      }
    // 2) next chunk's r pipeline now -> covered by MFMA phase below
    if (c + 1 < cend) {
      calcR(c + 1, w1p, b1p);
      bcastR();
      w1p += 64; b1p += 8;
    }
    // 3) MFMA phase
#pragma unroll
    for (int kg = 0; kg < 8; ++kg) {
      loadB((kg + 2) & 3);   // prefetch 2 kg-steps ahead (tail reads pad tiles)
#pragma unroll
      for (int mt = 0; mt < 2; ++mt) {
        f16x2 r2 = __builtin_bit_cast(f16x2, rsp[kg * 2 + mt]);
        u32x4 U;
#pragma unroll
        for (int j = 0; j < 4; ++j)
          U[j] = __builtin_bit_cast(unsigned,
                   __builtin_bit_cast(f16x2, xh16[mt][j]) * r2);
        f16x8 A = __builtin_bit_cast(f16x8, U);
#pragma unroll
        for (int nt = 0; nt < 2; ++nt)
          acc[mt][nt] = __builtin_amdgcn_mfma_f32_32x32x16_f16(A, Bs[kg & 3][nt], acc[mt][nt], 0, 0, 0);
      }
    }
  }

  // epilogue: scatter partial msg to agg[dst]
  // C layout: col(h-part)=l31, row=(reg&3)+8*(reg>>2)+4*half
#pragma unroll
  for (int mt = 0; mt < 2; ++mt) {
#pragma unroll
    for (int reg = 0; reg < 16; ++reg) {
      int el = mt * 32 + (reg & 3) + 8 * (reg >> 2) + 4 * half;
      int dd = __shfl(dstv, el);
      if (dd >= 0) {
#pragma unroll
        for (int nt = 0; nt < 2; ++nt)
          atomicAdd(&agg[(size_t)dd * 64 + nt * 32 + l31], acc[mt][nt][reg]);
      }
    }
  }
}

// ---------------- h = relu(x@rootw + agg/deg + b); LN1 partials ----------------
__global__ void k_root(const float* __restrict__ x, const float* __restrict__ rootw,
                       const float* __restrict__ conv1b, const float* __restrict__ agg,
                       const int* __restrict__ degI, float* __restrict__ hpre,
                       float* __restrict__ rpart) {
  __shared__ float sW[1024];
  __shared__ float sx[64];
  __shared__ float red[8];
  int t = threadIdx.x;
  int blk = blockIdx.x;
#pragma unroll
  for (int i = 0; i < 4; ++i) sW[t + i * 256] = rootw[t + i * 256];
  if (t < 64) sx[t] = x[(size_t)blk * 64 + t];
  __syncthreads();
  int ln = t >> 6, h = t & 63;
  int n = blk * 4 + ln;
  float acc = conv1b[h];
#pragma unroll
  for (int f = 0; f < 16; ++f) acc += sx[ln * 16 + f] * sW[f * 64 + h];
  float dv = fmaxf((float)degI[n], 1.0f);
  float v = acc + agg[(size_t)n * 64 + h] / dv;
  v = fmaxf(v, 0.f);
  hpre[(size_t)n * 64 + h] = v;
  float s1 = v, s2 = v * v;
  for (int o = 32; o > 0; o >>= 1) { s1 += __shfl_down(s1, o); s2 += __shfl_down(s2, o); }
  if ((t & 63) == 0) { red[t >> 6] = s1; red[4 + (t >> 6)] = s2; }
  __syncthreads();
  if (t == 0) {
    rpart[blk * 2] = red[0] + red[1] + red[2] + red[3];
    rpart[blk * 2 + 1] = red[4] + red[5] + red[6] + red[7];
  }
}

// reduce LN1 partials; fold LN1 into gat_w
__global__ void k_fold1(const float* __restrict__ rpart, const float* __restrict__ n1w,
                        const float* __restrict__ n1b, const float* __restrict__ gatw,
                        float* __restrict__ gw2, float* __restrict__ tb) {
  __shared__ float red[8];
  __shared__ float sMI[2];
  __shared__ float sS[64], sT[64];
  int t = threadIdx.x;
  int wv = t >> 6, lane = t & 63;
  float a = 0.f, b = 0.f;
  for (int i = t; i < NBLK_P; i += 256) { a += rpart[2 * i]; b += rpart[2 * i + 1]; }
  for (int o = 32; o > 0; o >>= 1) { a += __shfl_down(a, o); b += __shfl_down(b, o); }
  if (lane == 0) { red[wv] = a; red[4 + wv] = b; }
  __syncthreads();
  if (t == 0) {
    float A = red[0] + red[1] + red[2] + red[3];
    float B = red[4] + red[5] + red[6] + red[7];
    const float M = (float)N_NODES * 64.f;
    float mu = A / M;
    float var = fmaxf(B / M - mu * mu, 0.f);
    sMI[0] = mu;
    sMI[1] = 1.f / (sqrtf(var) + LNEPS);
  }
  __syncthreads();
  if (t < 64) {
    float mu = sMI[0], inv = sMI[1];
    sS[t] = inv * n1w[t];
    sT[t] = n1b[t] - mu * inv * n1w[t];
  }
  __syncthreads();
  if (t < 64) {
    float acc = 0.f;
    for (int i = 0; i < 64; ++i) {
      float g = gatw[i * 64 + t];
      gw2[i * 64 + t] = sS[i] * g;
      acc += sT[i] * g;
    }
    tb[t] = acc;
  }
}

// xh = hpre@gw2 + tb ; attention scalars
__global__ void k_gatlin(const float* __restrict__ hpre, const float* __restrict__ gw2,
                         const float* __restrict__ tb, const float* __restrict__ attS,
                         const float* __restrict__ attD, float* __restrict__ xh,
                         float* __restrict__ asrc, float* __restrict__ adst) {
  __shared__ float sW[4096];
  __shared__ float sh[256];
  __shared__ float sxh[256];
  int t = threadIdx.x;
  int blk = blockIdx.x;
#pragma unroll
  for (int i = 0; i < 16; ++i) sW[t + i * 256] = gw2[t + i * 256];
  sh[t] = hpre[(size_t)blk * 256 + t];
  __syncthreads();
  int ln = t >> 6, h = t & 63;
  float acc = tb[h];
  for (int i = 0; i < 64; ++i) acc += sh[ln * 64 + i] * sW[i * 64 + h];
  xh[(size_t)blk * 256 + t] = acc;
  sxh[t] = acc;
  __syncthreads();
  if (t < 32) {
    int ln2 = t >> 3, rem = t & 7;
    int hd = rem & 3;
    const float* av = (rem >> 2) ? attD : attS;
    float a = 0.f;
#pragma unroll
    for (int d = 0; d < 16; ++d) a += sxh[ln2 * 64 + hd * 16 + d] * av[hd * 16 + d];
    int n = blk * 4 + ln2;
    if (rem >> 2) adst[n * 4 + hd] = a; else asrc[n * 4 + hd] = a;
  }
}

// ---------------- GAT: CSR gather, online softmax, fused relu + LN2 partials ----------------
__global__ void k_gat(const int* __restrict__ rowptr, const int* __restrict__ colsrc,
                      const float* __restrict__ xh, const float* __restrict__ asrc,
                      const float* __restrict__ adst, const float* __restrict__ gatb,
                      float* __restrict__ act, float* __restrict__ gpart) {
  __shared__ float sP[4][256];
  __shared__ int sS[4][64];
  __shared__ float sRed[8];
  int t = threadIdx.x;
  int wv = t >> 6, lane = t & 63;
  int n = blockIdx.x * 4 + wv;
  int start = rowptr[n], end = rowptr[n + 1];
  int deg = end - start;
  int myhd = lane >> 4;
  float ad[4];
#pragma unroll
  for (int hd = 0; hd < 4; ++hd) ad[hd] = adst[n * 4 + hd];
  float m[4] = {-1e30f, -1e30f, -1e30f, -1e30f};
  float l[4] = {0.f, 0.f, 0.f, 0.f};
  float O = 0.f;
  int items = deg + 1;  // + self loop
  for (int t0 = 0; t0 < items; t0 += 64) {
    int cnt = min(64, items - t0);
    int idx = t0 + lane;
    bool has = lane < cnt;
    int s = n;
    if (has && idx < deg) s = colsrc[start + idx];
    float a[4];
#pragma unroll
    for (int hd = 0; hd < 4; ++hd) {
      float av = has ? (asrc[s * 4 + hd] + ad[hd]) : -1e30f;
      a[hd] = (av > 0.f) ? av : 0.2f * av;  // leaky relu 0.2
    }
    float tm[4];
#pragma unroll
    for (int hd = 0; hd < 4; ++hd) tm[hd] = a[hd];
#pragma unroll
    for (int off = 32; off > 0; off >>= 1)
#pragma unroll
      for (int hd = 0; hd < 4; ++hd) tm[hd] = fmaxf(tm[hd], __shfl_xor(tm[hd], off));
    float p[4];
#pragma unroll
    for (int hd = 0; hd < 4; ++hd) {
      float mn = fmaxf(m[hd], tm[hd]);
      float sc = __expf(m[hd] - mn);
      l[hd] *= sc;
      if (hd == myhd) O *= sc;
      m[hd] = mn;
      p[hd] = has ? __expf(a[hd] - mn) : 0.f;
    }
    float ts[4];
#pragma unroll
    for (int hd = 0; hd < 4; ++hd) ts[hd] = p[hd];
#pragma unroll
    for (int off = 32; off > 0; off >>= 1)
#pragma unroll
      for (int hd = 0; hd < 4; ++hd) ts[hd] += __shfl_xor(ts[hd], off);
#pragma unroll
    for (int hd = 0; hd < 4; ++hd) l[hd] += ts[hd];
    sS[wv][lane] = s;
#pragma unroll
    for (int hd = 0; hd < 4; ++hd) sP[wv][lane * 4 + hd] = p[hd];
    // wave-private LDS region: program order suffices, no barrier
    for (int e2 = 0; e2 < cnt; ++e2) {
      int ss = sS[wv][e2];
      float pp = sP[wv][e2 * 4 + myhd];
      O = fmaf(pp, xh[(size_t)ss * 64 + lane], O);
    }
  }
  float lmy = (myhd & 2) ? ((myhd & 1) ? l[3] : l[2]) : ((myhd & 1) ? l[1] : l[0]);
  float outv = O / (lmy + 1e-16f);
  float v = fmaxf(outv + gatb[lane], 0.f);
  act[(size_t)n * 64 + lane] = v;
  float s1 = v, s2 = v * v;
#pragma unroll
  for (int off = 32; off > 0; off >>= 1) { s1 += __shfl_down(s1, off); s2 += __shfl_down(s2, off); }
  if (lane == 0) { sRed[wv] = s1; sRed[4 + wv] = s2; }
  __syncthreads();
  if (t == 0) {
    gpart[blockIdx.x * 2] = sRed[0] + sRed[1] + sRed[2] + sRed[3];
    gpart[blockIdx.x * 2 + 1] = sRed[4] + sRed[5] + sRed[6] + sRed[7];
  }
}

// reduce LN2 partials; fold LN2 + linear head into wl
__global__ void k_fold2(const float* __restrict__ gpart, const float* __restrict__ n2w,
                        const float* __restrict__ n2b, const float* __restrict__ linw,
                        const float* __restrict__ linb, float* __restrict__ wl) {
  __shared__ float red[8];
  __shared__ float sMI[2];
  int t = threadIdx.x;
  int wv = t >> 6, lane = t & 63;
  float a = 0.f, b = 0.f;
  for (int i = t; i < NBLK_P; i += 256) { a += gpart[2 * i]; b += gpart[2 * i + 1]; }
  for (int o = 32; o > 0; o >>= 1) { a += __shfl_down(a, o); b += __shfl_down(b, o); }
  if (lane == 0) { red[wv] = a; red[4 + wv] = b; }
  __syncthreads();
  if (t == 0) {
    float A = red[0] + red[1] + red[2] + red[3];
    float B = red[4] + red[5] + red[6] + red[7];
    const float M = (float)N_NODES * 64.f;
    float mu = A / M;
    float var = fmaxf(B / M - mu * mu, 0.f);
    sMI[0] = mu;
    sMI[1] = 1.f / (sqrtf(var) + LNEPS);
  }
  __syncthreads();
  if (t < 64) {
    float mu = sMI[0], inv = sMI[1];
    float w = inv * n2w[t] * linw[t];
    float p = (n2b[t] - mu * inv * n2w[t]) * linw[t];
    wl[t] = w;
    for (int o = 32; o > 0; o >>= 1) p += __shfl_down(p, o);
    if (t == 0) wl[64] = p + linb[0];
  }
}

// per-graph segmented pool + head (batch is sorted; zero atomics)
__global__ void k_out(const float* __restrict__ act, const float* __restrict__ wl,
                      const int* __restrict__ batch, float* __restrict__ out) {
  __shared__ float red[4];
  __shared__ float swl[64];
  int g = blockIdx.x;
  int t = threadIdx.x;
  int wv = t >> 6, lane = t & 63;
  if (t < 64) swl[t] = wl[t];
  __syncthreads();
  auto lbound = [&](int key) {
    int lo = 0, hi = N_NODES;
    while (lo < hi) { int mid = (lo + hi) >> 1; if (batch[mid] < key) lo = mid + 1; else hi = mid; }
    return lo;
  };
  int lo = lbound(g), hi = lbound(g + 1);
  int cntn = hi - lo;
  float s = 0.f;
  for (int idx = t; idx < cntn * 64; idx += 256) {
    int n = lo + (idx >> 6);
    int d = idx & 63;
    s += act[(size_t)n * 64 + d] * swl[d];
  }
  for (int o = 32; o > 0; o >>= 1) s += __shfl_down(s, o);
  if (lane == 0) red[wv] = s;
  __syncthreads();
  if (t == 0)
    out[g] = (red[0] + red[1] + red[2] + red[3]) / fmaxf((float)cntn, 1.f) + wl[64];
}

// ---------------- workspace layout (bytes, 64B aligned) ----------------
#define OFF_AGG     0UL
#define OFF_DEGI    12800000UL
#define ZBYTES      13000000UL
#define OFF_RPART   13000000UL
#define OFF_GPART   13100032UL
#define OFF_ROWPTR  13200064UL
#define OFF_CURSOR  13400128UL
#define OFF_BSUM    13600192UL
#define OFF_BPRE    13601024UL
#define OFF_COLSRC  13601856UL
#define OFF_TT      14801856UL   // NKG*1024*2 = 2117632
#define OFF_W1T     16923584UL
#define OFF_GW2     16956352UL
#define OFF_TB      16972736UL
#define OFF_WL      16972992UL
#define OFF_ASRC    16973312UL
#define OFF_ADST    17773312UL
#define OFF_HPRE    18573312UL
#define OFF_XH      31373312UL
#define OFF_ACT     44173312UL
#define WS_NEED     56973312UL

extern "C" void kernel_launch(void* const* d_in, const int* in_sizes, int n_in,
                              void* d_out, int out_size, void* d_ws, size_t ws_size,
                              hipStream_t stream) {
  const float* x = (const float*)d_in[0];
  const int* ei = (const int*)d_in[1];
  const float* ea = (const float*)d_in[2];
  const int* batch = (const int*)d_in[3];
  const float* w1 = (const float*)d_in[4];
  const float* b1 = (const float*)d_in[5];
  const float* w2 = (const float*)d_in[6];
  const float* b2 = (const float*)d_in[7];
  const float* rootw = (const float*)d_in[8];
  const float* conv1b = (const float*)d_in[9];
  const float* n1w = (const float*)d_in[10];
  const float* n1b = (const float*)d_in[11];
  const float* gatw = (const float*)d_in[12];
  const float* attS = (const float*)d_in[13];
  const float* attD = (const float*)d_in[14];
  const float* gatb = (const float*)d_in[15];
  const float* n2w = (const float*)d_in[16];
  const float* n2b = (const float*)d_in[17];
  const float* linw = (const float*)d_in[18];
  const float* linb = (const float*)d_in[19];

  if (ws_size < WS_NEED) return;
  char* ws = (char*)d_ws;
  float* agg    = (float*)(ws + OFF_AGG);
  int* degI     = (int*)(ws + OFF_DEGI);
  float* rpart  = (float*)(ws + OFF_RPART);
  float* gpart  = (float*)(ws + OFF_GPART);
  int* rowptr   = (int*)(ws + OFF_ROWPTR);
  int* cursor   = (int*)(ws + OFF_CURSOR);
  int* bsum     = (int*)(ws + OFF_BSUM);
  int* bpre     = (int*)(ws + OFF_BPRE);
  int* colsrc   = (int*)(ws + OFF_COLSRC);
  _Float16* Tt3 = (_Float16*)(ws + OFF_TT);
  float* W1t    = (float*)(ws + OFF_W1T);
  float* gw2    = (float*)(ws + OFF_GW2);
  float* tb     = (float*)(ws + OFF_TB);
  float* wl     = (float*)(ws + OFF_WL);
  float* asrc   = (float*)(ws + OFF_ASRC);
  float* adst   = (float*)(ws + OFF_ADST);
  float* hpre   = (float*)(ws + OFF_HPRE);
  float* xh     = (float*)(ws + OFF_XH);
  float* act    = (float*)(ws + OFF_ACT);

  hipMemsetAsync(ws, 0, ZBYTES, stream);

  k_prep<<<NKG * 4, 256, 0, stream>>>(w2, b2, Tt3);   // NKG*1024/256
  k_prepw<<<32, 256, 0, stream>>>(w1, W1t);
  k_cnt<<<(E_EDGES + 255) / 256, 256, 0, stream>>>(ei, degI);
  k_scanA<<<NBLK_N, 256, 0, stream>>>(degI, bsum);
  k_scanB<<<1, 256, 0, stream>>>(bsum, bpre);
  k_scanC<<<NBLK_N, 256, 0, stream>>>(degI, bpre, rowptr, cursor);
  k_scatter<<<(E_EDGES + 255) / 256, 256, 0, stream>>>(ei, cursor, colsrc);
  k_nnconv<<<NEGRP * 2, 256, 0, stream>>>(x, ei, ea, W1t, b1, Tt3, agg);
  k_root<<<NBLK_P, 256, 0, stream>>>(x, rootw, conv1b, agg, degI, hpre, rpart);
  k_fold1<<<1, 256, 0, stream>>>(rpart, n1w, n1b, gatw, gw2, tb);
  k_gatlin<<<NBLK_P, 256, 0, stream>>>(hpre, gw2, tb, attS, attD, xh, asrc, adst);
  k_gat<<<NBLK_P, 256, 0, stream>>>(rowptr, colsrc, xh, asrc, adst, gatb, act, gpart);
  k_fold2<<<1, 256, 0, stream>>>(gpart, n2w, n2b, linw, linb, wl);
  k_out<<<NGRAPH, 256, 0, stream>>>(act, wl, batch, (float*)d_out);
}

// Round 11
// 968.470 us; speedup vs baseline: 1.2216x; 1.0375x over previous
//
#include <hip/hip_runtime.h>
#include <hip/hip_bf16.h>

#define N_NODES 50000
#define E_EDGES 300000
#define NGRAPH 64
#define NCHUNK 129
#define CSPLIT 65    // piece 0: c in [0,65), piece 1: [65,129)
#define NKG 1034     // 129*8 kgroups + 2 pad (prefetch distance 2 overrun)
#define NEGRP 1172   // ceil(E/256)
#define LNEPS 1e-5f
#define NBLK_N 196   // ceil(50000/256)
#define NBLK_P 12500 // N_NODES/4
// prescale so RTZ pack to f16 ~= round-to-nearest
#define RPRE16 1.00048828125f

typedef _Float16 f16x8 __attribute__((ext_vector_type(8)));
typedef _Float16 f16x2 __attribute__((ext_vector_type(2)));
typedef float floatx16 __attribute__((ext_vector_type(16)));
typedef float f32x2 __attribute__((ext_vector_type(2)));
typedef unsigned int u32x4 __attribute__((ext_vector_type(4)));

// ---------------- prep: Tt3[kg][half][n][j] f16, coalesced via LDS transpose ----------------
// element (kg, half, n, j) = T[kf = kg*16 + half*8 + j][n]; per-kg tile = 1024 f16 (2 KB).
// Reads: w2 flat = kf*64 + n -> row-major coalesced into tile; writes: 16B/thread coalesced.
__global__ void k_prep(const float* __restrict__ w2, const float* __restrict__ b2,
                       _Float16* __restrict__ Tt3) {
  __shared__ float tile[32][65];
  int t = threadIdx.x;
  int kg0 = blockIdx.x * 2;       // 2 kg-tiles per block, 517 blocks
  int kf0 = kg0 * 16;
  int kfr = t >> 6;               // 0..3
  int n0 = t & 63;
#pragma unroll
  for (int it = 0; it < 8; ++it) {
    int kfl = it * 4 + kfr;
    int kf = kf0 + kfl;
    float v = 0.f;
    if (kf < 16384) v = w2[(size_t)kf * 64 + n0];
    else if (kf < 16400) v = b2[(size_t)(kf - 16384) * 64 + n0];
    tile[kfl][n0] = v;
  }
  __syncthreads();
  int kgl = t >> 7;               // 0..1
  int half = (t >> 6) & 1;
  int n = t & 63;
  f16x8 pack;
#pragma unroll
  for (int j = 0; j < 8; ++j) pack[j] = (_Float16)tile[kgl * 16 + half * 8 + j][n];
  *(f16x8*)(Tt3 + (size_t)(kg0 + kgl) * 1024 + half * 512 + n * 8) = pack;
}

__global__ void k_prepw(const float* __restrict__ w1, float* __restrict__ W1t) {
  int i = blockIdx.x * 256 + threadIdx.x;
  if (i < 8192) { int k = i >> 3, j = i & 7; W1t[i] = w1[j * 1024 + k]; }
}

// ---------------- CSR build ----------------
__global__ void k_cnt(const int* __restrict__ ei, int* __restrict__ degI) {
  int e = blockIdx.x * 256 + threadIdx.x;
  if (e < E_EDGES) atomicAdd(&degI[ei[E_EDGES + e]], 1);
}

__global__ void k_scanA(const int* __restrict__ degI, int* __restrict__ bsum) {
  __shared__ int sm[256];
  int t = threadIdx.x;
  int i = blockIdx.x * 256 + t;
  sm[t] = (i < N_NODES) ? degI[i] : 0;
  __syncthreads();
  for (int off = 128; off > 0; off >>= 1) {
    if (t < off) sm[t] += sm[t + off];
    __syncthreads();
  }
  if (t == 0) bsum[blockIdx.x] = sm[0];
}

__global__ void k_scanB(const int* __restrict__ bsum, int* __restrict__ bpre) {
  __shared__ int s[256];
  int t = threadIdx.x;
  int v = (t < NBLK_N) ? bsum[t] : 0;
  s[t] = v;
  __syncthreads();
  for (int off = 1; off < 256; off <<= 1) {
    int add = (t >= off) ? s[t - off] : 0;
    __syncthreads();
    s[t] += add;
    __syncthreads();
  }
  if (t < NBLK_N) bpre[t] = s[t] - v;
}

__global__ void k_scanC(const int* __restrict__ degI, const int* __restrict__ bpre,
                        int* __restrict__ rowptr, int* __restrict__ cursor) {
  __shared__ int s[256];
  int t = threadIdx.x;
  int i = blockIdx.x * 256 + t;
  int d = (i < N_NODES) ? degI[i] : 0;
  s[t] = d;
  __syncthreads();
  for (int off = 1; off < 256; off <<= 1) {
    int add = (t >= off) ? s[t - off] : 0;
    __syncthreads();
    s[t] += add;
    __syncthreads();
  }
  int r = bpre[blockIdx.x] + s[t] - d;   // exclusive
  if (i < N_NODES) {
    rowptr[i] = r;
    cursor[i] = r;
    if (i == N_NODES - 1) rowptr[N_NODES] = r + d;
  }
}

__global__ void k_scatter(const int* __restrict__ ei, int* __restrict__ cursor,
                          int* __restrict__ colsrc) {
  int e = blockIdx.x * 256 + threadIdx.x;
  if (e < E_EDGES) {
    int s = ei[e], d = ei[E_EDGES + e];
    int pos = atomicAdd(&cursor[d], 1);
    colsrc[pos] = s;
  }
}

// ---------------- NNConv fused MFMA GEMM, split-K x2, 32x32x16 f16 ----------------
// R11: __launch_bounds__(256,4) — R10 measured exactly 64 VGPR + 64 AGPR = 128/wave,
// the 4-waves/SIMD boundary; force allocator to that cap for 4 blocks/CU residency.
// (R3's spill was a kernel wanting ~154 regs under the 128 cap; this one needs 128.)
// Layouts: A[m][k]: m=lane&31, k=(lane>>5)*8+j. B[k][n]: n=lane&31, k=(lane>>5)*8+j.
// C/D: col=lane&31, row=(reg&3)+8*(reg>>2)+4*(lane>>5)  [m74/m101 verified].
__global__ __launch_bounds__(256, 4)
void k_nnconv(const float* __restrict__ x, const int* __restrict__ ei,
              const float* __restrict__ ea, const float* __restrict__ W1t,
              const float* __restrict__ b1, const _Float16* __restrict__ Tt3,
              float* __restrict__ agg) {
  const int tid = threadIdx.x;
  const int lane = tid & 63;
  const int l31 = lane & 31;
  const int half = lane >> 5;
  const int grp = blockIdx.x >> 1;
  const int piece = blockIdx.x & 1;
  const int cstart = piece ? CSPLIT : 0;
  const int cend = piece ? NCHUNK : CSPLIT;

  int e = grp * 256 + tid;
  bool valid = e < E_EDGES;
  int srcv = valid ? ei[e] : 0;
  int dstv = valid ? ei[E_EDGES + e] : -1;

  f32x2 ea2[4];
  {
    const float4* p = (const float4*)(ea + (size_t)(valid ? e : 0) * 8);
    float4 a0 = p[0], a1 = p[1];
    ea2[0] = (f32x2){a0.x, a0.y};
    ea2[1] = (f32x2){a0.z, a0.w};
    ea2[2] = (f32x2){a1.x, a1.y};
    ea2[3] = (f32x2){a1.z, a1.w};
  }

  // persistent x fragments: mt in {0,1}, edge m = mt*32+l31, f = half*8 + j
  const int f0 = half * 8;
  unsigned xh16[2][4];
#pragma unroll
  for (int mt = 0; mt < 2; ++mt) {
    int s = __shfl(srcv, mt * 32 + l31);
    const float4* px = (const float4*)(x + (size_t)s * 16 + f0);
    float4 v0 = px[0], v1 = px[1];
    xh16[mt][0] = __builtin_bit_cast(unsigned, __builtin_amdgcn_cvt_pkrtz(v0.x * RPRE16, v0.y * RPRE16));
    xh16[mt][1] = __builtin_bit_cast(unsigned, __builtin_amdgcn_cvt_pkrtz(v0.z * RPRE16, v0.w * RPRE16));
    xh16[mt][2] = __builtin_bit_cast(unsigned, __builtin_amdgcn_cvt_pkrtz(v1.x * RPRE16, v1.y * RPRE16));
    xh16[mt][3] = __builtin_bit_cast(unsigned, __builtin_amdgcn_cvt_pkrtz(v1.z * RPRE16, v1.w * RPRE16));
  }

  // bpermute byte addresses: lane wants r of edge (mt*32 + l31)
  int bpaddr[2];
#pragma unroll
  for (int mt = 0; mt < 2; ++mt) bpaddr[mt] = (mt * 32 + l31) * 4;

  // B stream: uniform base (advances 1024 elems/kg) + fixed lane offset
  const _Float16* sb = Tt3 + (size_t)(cstart * 8) * 1024;
  const int loff = half * 512 + l31 * 8;   // elements

  f16x8 Bs[4][2];   // 4 slots x 2 ntiles x 4 regs = 32 VGPRs
  auto loadB = [&](int slot) {
    Bs[slot][0] = *(const f16x8*)(sb + loff);
    Bs[slot][1] = *(const f16x8*)(sb + loff + 256);  // ntile 1: n += 32 -> +32*8 elems
    sb += 1024;
  };

  unsigned prr[4];   // f16-packed r pair: lo16=r[2p], hi16=r[2p+1]
  auto calcR = [&](int c, const float* w1p, const float* b1p) {
    if (c < 128) {   // uniform branch
#pragma unroll
      for (int p = 0; p < 4; ++p) {
        float rv[2];
#pragma unroll
        for (int kk = 0; kk < 2; ++kk) {
          const f32x2* w = (const f32x2*)(w1p + (p * 2 + kk) * 8);  // uniform -> s_load
          f32x2 s01 = ea2[0] * w[0] + ea2[1] * w[1];
          f32x2 s23 = ea2[2] * w[2] + ea2[3] * w[3];
          f32x2 s = s01 + s23;
          rv[kk] = fmaxf(b1p[p * 2 + kk] + s[0] + s[1], 0.f) * RPRE16;
        }
        prr[p] = __builtin_bit_cast(unsigned, __builtin_amdgcn_cvt_pkrtz(rv[0], rv[1]));
      }
    } else {
      prr[0] = 0x00003C00u;  // lo16 = f16(1.0) at k=1024 (b2 rows); rest 0
      prr[1] = prr[2] = prr[3] = 0u;
    }
  };

  unsigned ubuf[8]; // bpermuted r pairs for CURRENT chunk: [pair*2 + mt]
  auto bcastR = [&]() {
#pragma unroll
    for (int p = 0; p < 4; ++p)
#pragma unroll
      for (int mt = 0; mt < 2; ++mt)
        ubuf[p * 2 + mt] = (unsigned)__builtin_amdgcn_ds_bpermute(bpaddr[mt], (int)prr[p]);
  };

  floatx16 acc[2][2];
#pragma unroll
  for (int mt = 0; mt < 2; ++mt)
#pragma unroll
    for (int nt = 0; nt < 2; ++nt)
#pragma unroll
      for (int r = 0; r < 16; ++r) acc[mt][nt][r] = 0.f;

  calcR(cstart, W1t + cstart * 64, b1 + cstart * 8);
  bcastR();
  loadB(0);
  loadB(1);
  const float* w1p = W1t + (cstart + 1) * 64;
  const float* b1p = b1 + (cstart + 1) * 8;

  for (int c = cstart; c < cend; ++c) {
    // 1) extract all splatted r values for this chunk (kg 0..7 x mt)
    unsigned rsp[16];
#pragma unroll
    for (int p = 0; p < 4; ++p)
#pragma unroll
      for (int mt = 0; mt < 2; ++mt) {
        unsigned u = ubuf[p * 2 + mt];
        rsp[(2 * p) * 2 + mt]     = __builtin_amdgcn_perm(u, 0u, 0x05040504u); // lo half
        rsp[(2 * p + 1) * 2 + mt] = __builtin_amdgcn_perm(u, 0u, 0x07060706u); // hi half
      }
    // 2) next chunk's r pipeline now -> covered by MFMA phase below
    if (c + 1 < cend) {
      calcR(c + 1, w1p, b1p);
      bcastR();
      w1p += 64; b1p += 8;
    }
    // 3) MFMA phase
#pragma unroll
    for (int kg = 0; kg < 8; ++kg) {
      loadB((kg + 2) & 3);   // prefetch 2 kg-steps ahead (tail reads pad tiles)
#pragma unroll
      for (int mt = 0; mt < 2; ++mt) {
        f16x2 r2 = __builtin_bit_cast(f16x2, rsp[kg * 2 + mt]);
        u32x4 U;
#pragma unroll
        for (int j = 0; j < 4; ++j)
          U[j] = __builtin_bit_cast(unsigned,
                   __builtin_bit_cast(f16x2, xh16[mt][j]) * r2);
        f16x8 A = __builtin_bit_cast(f16x8, U);
#pragma unroll
        for (int nt = 0; nt < 2; ++nt)
          acc[mt][nt] = __builtin_amdgcn_mfma_f32_32x32x16_f16(A, Bs[kg & 3][nt], acc[mt][nt], 0, 0, 0);
      }
    }
  }

  // epilogue: scatter partial msg to agg[dst]
  // C layout: col(h-part)=l31, row=(reg&3)+8*(reg>>2)+4*half
#pragma unroll
  for (int mt = 0; mt < 2; ++mt) {
#pragma unroll
    for (int reg = 0; reg < 16; ++reg) {
      int el = mt * 32 + (reg & 3) + 8 * (reg >> 2) + 4 * half;
      int dd = __shfl(dstv, el);
      if (dd >= 0) {
#pragma unroll
        for (int nt = 0; nt < 2; ++nt)
          atomicAdd(&agg[(size_t)dd * 64 + nt * 32 + l31], acc[mt][nt][reg]);
      }
    }
  }
}

// ---------------- h = relu(x@rootw + agg/deg + b); LN1 partials ----------------
__global__ void k_root(const float* __restrict__ x, const float* __restrict__ rootw,
                       const float* __restrict__ conv1b, const float* __restrict__ agg,
                       const int* __restrict__ degI, float* __restrict__ hpre,
                       float* __restrict__ rpart) {
  __shared__ float sW[1024];
  __shared__ float sx[64];
  __shared__ float red[8];
  int t = threadIdx.x;
  int blk = blockIdx.x;
#pragma unroll
  for (int i = 0; i < 4; ++i) sW[t + i * 256] = rootw[t + i * 256];
  if (t < 64) sx[t] = x[(size_t)blk * 64 + t];
  __syncthreads();
  int ln = t >> 6, h = t & 63;
  int n = blk * 4 + ln;
  float acc = conv1b[h];
#pragma unroll
  for (int f = 0; f < 16; ++f) acc += sx[ln * 16 + f] * sW[f * 64 + h];
  float dv = fmaxf((float)degI[n], 1.0f);
  float v = acc + agg[(size_t)n * 64 + h] / dv;
  v = fmaxf(v, 0.f);
  hpre[(size_t)n * 64 + h] = v;
  float s1 = v, s2 = v * v;
  for (int o = 32; o > 0; o >>= 1) { s1 += __shfl_down(s1, o); s2 += __shfl_down(s2, o); }
  if ((t & 63) == 0) { red[t >> 6] = s1; red[4 + (t >> 6)] = s2; }
  __syncthreads();
  if (t == 0) {
    rpart[blk * 2] = red[0] + red[1] + red[2] + red[3];
    rpart[blk * 2 + 1] = red[4] + red[5] + red[6] + red[7];
  }
}

// reduce LN1 partials; fold LN1 into gat_w
__global__ void k_fold1(const float* __restrict__ rpart, const float* __restrict__ n1w,
                        const float* __restrict__ n1b, const float* __restrict__ gatw,
                        float* __restrict__ gw2, float* __restrict__ tb) {
  __shared__ float red[8];
  __shared__ float sMI[2];
  __shared__ float sS[64], sT[64];
  int t = threadIdx.x;
  int wv = t >> 6, lane = t & 63;
  float a = 0.f, b = 0.f;
  for (int i = t; i < NBLK_P; i += 256) { a += rpart[2 * i]; b += rpart[2 * i + 1]; }
  for (int o = 32; o > 0; o >>= 1) { a += __shfl_down(a, o); b += __shfl_down(b, o); }
  if (lane == 0) { red[wv] = a; red[4 + wv] = b; }
  __syncthreads();
  if (t == 0) {
    float A = red[0] + red[1] + red[2] + red[3];
    float B = red[4] + red[5] + red[6] + red[7];
    const float M = (float)N_NODES * 64.f;
    float mu = A / M;
    float var = fmaxf(B / M - mu * mu, 0.f);
    sMI[0] = mu;
    sMI[1] = 1.f / (sqrtf(var) + LNEPS);
  }
  __syncthreads();
  if (t < 64) {
    float mu = sMI[0], inv = sMI[1];
    sS[t] = inv * n1w[t];
    sT[t] = n1b[t] - mu * inv * n1w[t];
  }
  __syncthreads();
  if (t < 64) {
    float acc = 0.f;
    for (int i = 0; i < 64; ++i) {
      float g = gatw[i * 64 + t];
      gw2[i * 64 + t] = sS[i] * g;
      acc += sT[i] * g;
    }
    tb[t] = acc;
  }
}

// xh = hpre@gw2 + tb ; attention scalars
__global__ void k_gatlin(const float* __restrict__ hpre, const float* __restrict__ gw2,
                         const float* __restrict__ tb, const float* __restrict__ attS,
                         const float* __restrict__ attD, float* __restrict__ xh,
                         float* __restrict__ asrc, float* __restrict__ adst) {
  __shared__ float sW[4096];
  __shared__ float sh[256];
  __shared__ float sxh[256];
  int t = threadIdx.x;
  int blk = blockIdx.x;
#pragma unroll
  for (int i = 0; i < 16; ++i) sW[t + i * 256] = gw2[t + i * 256];
  sh[t] = hpre[(size_t)blk * 256 + t];
  __syncthreads();
  int ln = t >> 6, h = t & 63;
  float acc = tb[h];
  for (int i = 0; i < 64; ++i) acc += sh[ln * 64 + i] * sW[i * 64 + h];
  xh[(size_t)blk * 256 + t] = acc;
  sxh[t] = acc;
  __syncthreads();
  if (t < 32) {
    int ln2 = t >> 3, rem = t & 7;
    int hd = rem & 3;
    const float* av = (rem >> 2) ? attD : attS;
    float a = 0.f;
#pragma unroll
    for (int d = 0; d < 16; ++d) a += sxh[ln2 * 64 + hd * 16 + d] * av[hd * 16 + d];
    int n = blk * 4 + ln2;
    if (rem >> 2) adst[n * 4 + hd] = a; else asrc[n * 4 + hd] = a;
  }
}

// ---------------- GAT: CSR gather, online softmax, fused relu + LN2 partials ----------------
__global__ void k_gat(const int* __restrict__ rowptr, const int* __restrict__ colsrc,
                      const float* __restrict__ xh, const float* __restrict__ asrc,
                      const float* __restrict__ adst, const float* __restrict__ gatb,
                      float* __restrict__ act, float* __restrict__ gpart) {
  __shared__ float sP[4][256];
  __shared__ int sS[4][64];
  __shared__ float sRed[8];
  int t = threadIdx.x;
  int wv = t >> 6, lane = t & 63;
  int n = blockIdx.x * 4 + wv;
  int start = rowptr[n], end = rowptr[n + 1];
  int deg = end - start;
  int myhd = lane >> 4;
  float ad[4];
#pragma unroll
  for (int hd = 0; hd < 4; ++hd) ad[hd] = adst[n * 4 + hd];
  float m[4] = {-1e30f, -1e30f, -1e30f, -1e30f};
  float l[4] = {0.f, 0.f, 0.f, 0.f};
  float O = 0.f;
  int items = deg + 1;  // + self loop
  for (int t0 = 0; t0 < items; t0 += 64) {
    int cnt = min(64, items - t0);
    int idx = t0 + lane;
    bool has = lane < cnt;
    int s = n;
    if (has && idx < deg) s = colsrc[start + idx];
    float a[4];
#pragma unroll
    for (int hd = 0; hd < 4; ++hd) {
      float av = has ? (asrc[s * 4 + hd] + ad[hd]) : -1e30f;
      a[hd] = (av > 0.f) ? av : 0.2f * av;  // leaky relu 0.2
    }
    float tm[4];
#pragma unroll
    for (int hd = 0; hd < 4; ++hd) tm[hd] = a[hd];
#pragma unroll
    for (int off = 32; off > 0; off >>= 1)
#pragma unroll
      for (int hd = 0; hd < 4; ++hd) tm[hd] = fmaxf(tm[hd], __shfl_xor(tm[hd], off));
    float p[4];
#pragma unroll
    for (int hd = 0; hd < 4; ++hd) {
      float mn = fmaxf(m[hd], tm[hd]);
      float sc = __expf(m[hd] - mn);
      l[hd] *= sc;
      if (hd == myhd) O *= sc;
      m[hd] = mn;
      p[hd] = has ? __expf(a[hd] - mn) : 0.f;
    }
    float ts[4];
#pragma unroll
    for (int hd = 0; hd < 4; ++hd) ts[hd] = p[hd];
#pragma unroll
    for (int off = 32; off > 0; off >>= 1)
#pragma unroll
      for (int hd = 0; hd < 4; ++hd) ts[hd] += __shfl_xor(ts[hd], off);
#pragma unroll
    for (int hd = 0; hd < 4; ++hd) l[hd] += ts[hd];
    sS[wv][lane] = s;
#pragma unroll
    for (int hd = 0; hd < 4; ++hd) sP[wv][lane * 4 + hd] = p[hd];
    // wave-private LDS region: program order suffices, no barrier
    for (int e2 = 0; e2 < cnt; ++e2) {
      int ss = sS[wv][e2];
      float pp = sP[wv][e2 * 4 + myhd];
      O = fmaf(pp, xh[(size_t)ss * 64 + lane], O);
    }
  }
  float lmy = (myhd & 2) ? ((myhd & 1) ? l[3] : l[2]) : ((myhd & 1) ? l[1] : l[0]);
  float outv = O / (lmy + 1e-16f);
  float v = fmaxf(outv + gatb[lane], 0.f);
  act[(size_t)n * 64 + lane] = v;
  float s1 = v, s2 = v * v;
#pragma unroll
  for (int off = 32; off > 0; off >>= 1) { s1 += __shfl_down(s1, off); s2 += __shfl_down(s2, off); }
  if (lane == 0) { sRed[wv] = s1; sRed[4 + wv] = s2; }
  __syncthreads();
  if (t == 0) {
    gpart[blockIdx.x * 2] = sRed[0] + sRed[1] + sRed[2] + sRed[3];
    gpart[blockIdx.x * 2 + 1] = sRed[4] + sRed[5] + sRed[6] + sRed[7];
  }
}

// reduce LN2 partials; fold LN2 + linear head into wl
__global__ void k_fold2(const float* __restrict__ gpart, const float* __restrict__ n2w,
                        const float* __restrict__ n2b, const float* __restrict__ linw,
                        const float* __restrict__ linb, float* __restrict__ wl) {
  __shared__ float red[8];
  __shared__ float sMI[2];
  int t = threadIdx.x;
  int wv = t >> 6, lane = t & 63;
  float a = 0.f, b = 0.f;
  for (int i = t; i < NBLK_P; i += 256) { a += gpart[2 * i]; b += gpart[2 * i + 1]; }
  for (int o = 32; o > 0; o >>= 1) { a += __shfl_down(a, o); b += __shfl_down(b, o); }
  if (lane == 0) { red[wv] = a; red[4 + wv] = b; }
  __syncthreads();
  if (t == 0) {
    float A = red[0] + red[1] + red[2] + red[3];
    float B = red[4] + red[5] + red[6] + red[7];
    const float M = (float)N_NODES * 64.f;
    float mu = A / M;
    float var = fmaxf(B / M - mu * mu, 0.f);
    sMI[0] = mu;
    sMI[1] = 1.f / (sqrtf(var) + LNEPS);
  }
  __syncthreads();
  if (t < 64) {
    float mu = sMI[0], inv = sMI[1];
    float w = inv * n2w[t] * linw[t];
    float p = (n2b[t] - mu * inv * n2w[t]) * linw[t];
    wl[t] = w;
    for (int o = 32; o > 0; o >>= 1) p += __shfl_down(p, o);
    if (t == 0) wl[64] = p + linb[0];
  }
}

// per-graph segmented pool + head (batch is sorted; zero atomics)
__global__ void k_out(const float* __restrict__ act, const float* __restrict__ wl,
                      const int* __restrict__ batch, float* __restrict__ out) {
  __shared__ float red[4];
  __shared__ float swl[64];
  int g = blockIdx.x;
  int t = threadIdx.x;
  int wv = t >> 6, lane = t & 63;
  if (t < 64) swl[t] = wl[t];
  __syncthreads();
  auto lbound = [&](int key) {
    int lo = 0, hi = N_NODES;
    while (lo < hi) { int mid = (lo + hi) >> 1; if (batch[mid] < key) lo = mid + 1; else hi = mid; }
    return lo;
  };
  int lo = lbound(g), hi = lbound(g + 1);
  int cntn = hi - lo;
  float s = 0.f;
  for (int idx = t; idx < cntn * 64; idx += 256) {
    int n = lo + (idx >> 6);
    int d = idx & 63;
    s += act[(size_t)n * 64 + d] * swl[d];
  }
  for (int o = 32; o > 0; o >>= 1) s += __shfl_down(s, o);
  if (lane == 0) red[wv] = s;
  __syncthreads();
  if (t == 0)
    out[g] = (red[0] + red[1] + red[2] + red[3]) / fmaxf((float)cntn, 1.f) + wl[64];
}

// ---------------- workspace layout (bytes, 64B aligned) ----------------
#define OFF_AGG     0UL
#define OFF_DEGI    12800000UL
#define ZBYTES      13000000UL
#define OFF_RPART   13000000UL
#define OFF_GPART   13100032UL
#define OFF_ROWPTR  13200064UL
#define OFF_CURSOR  13400128UL
#define OFF_BSUM    13600192UL
#define OFF_BPRE    13601024UL
#define OFF_COLSRC  13601856UL
#define OFF_TT      14801856UL   // NKG*1024*2 = 2117632
#define OFF_W1T     16923584UL
#define OFF_GW2     16956352UL
#define OFF_TB      16972736UL
#define OFF_WL      16972992UL
#define OFF_ASRC    16973312UL
#define OFF_ADST    17773312UL
#define OFF_HPRE    18573312UL
#define OFF_XH      31373312UL
#define OFF_ACT     44173312UL
#define WS_NEED     56973312UL

extern "C" void kernel_launch(void* const* d_in, const int* in_sizes, int n_in,
                              void* d_out, int out_size, void* d_ws, size_t ws_size,
                              hipStream_t stream) {
  const float* x = (const float*)d_in[0];
  const int* ei = (const int*)d_in[1];
  const float* ea = (const float*)d_in[2];
  const int* batch = (const int*)d_in[3];
  const float* w1 = (const float*)d_in[4];
  const float* b1 = (const float*)d_in[5];
  const float* w2 = (const float*)d_in[6];
  const float* b2 = (const float*)d_in[7];
  const float* rootw = (const float*)d_in[8];
  const float* conv1b = (const float*)d_in[9];
  const float* n1w = (const float*)d_in[10];
  const float* n1b = (const float*)d_in[11];
  const float* gatw = (const float*)d_in[12];
  const float* attS = (const float*)d_in[13];
  const float* attD = (const float*)d_in[14];
  const float* gatb = (const float*)d_in[15];
  const float* n2w = (const float*)d_in[16];
  const float* n2b = (const float*)d_in[17];
  const float* linw = (const float*)d_in[18];
  const float* linb = (const float*)d_in[19];

  if (ws_size < WS_NEED) return;
  char* ws = (char*)d_ws;
  float* agg    = (float*)(ws + OFF_AGG);
  int* degI     = (int*)(ws + OFF_DEGI);
  float* rpart  = (float*)(ws + OFF_RPART);
  float* gpart  = (float*)(ws + OFF_GPART);
  int* rowptr   = (int*)(ws + OFF_ROWPTR);
  int* cursor   = (int*)(ws + OFF_CURSOR);
  int* bsum     = (int*)(ws + OFF_BSUM);
  int* bpre     = (int*)(ws + OFF_BPRE);
  int* colsrc   = (int*)(ws + OFF_COLSRC);
  _Float16* Tt3 = (_Float16*)(ws + OFF_TT);
  float* W1t    = (float*)(ws + OFF_W1T);
  float* gw2    = (float*)(ws + OFF_GW2);
  float* tb     = (float*)(ws + OFF_TB);
  float* wl     = (float*)(ws + OFF_WL);
  float* asrc   = (float*)(ws + OFF_ASRC);
  float* adst   = (float*)(ws + OFF_ADST);
  float* hpre   = (float*)(ws + OFF_HPRE);
  float* xh     = (float*)(ws + OFF_XH);
  float* act    = (float*)(ws + OFF_ACT);

  hipMemsetAsync(ws, 0, ZBYTES, stream);

  k_prep<<<(NKG + 1) / 2, 256, 0, stream>>>(w2, b2, Tt3);
  k_prepw<<<32, 256, 0, stream>>>(w1, W1t);
  k_cnt<<<(E_EDGES + 255) / 256, 256, 0, stream>>>(ei, degI);
  k_scanA<<<NBLK_N, 256, 0, stream>>>(degI, bsum);
  k_scanB<<<1, 256, 0, stream>>>(bsum, bpre);
  k_scanC<<<NBLK_N, 256, 0, stream>>>(degI, bpre, rowptr, cursor);
  k_scatter<<<(E_EDGES + 255) / 256, 256, 0, stream>>>(ei, cursor, colsrc);
  k_nnconv<<<NEGRP * 2, 256, 0, stream>>>(x, ei, ea, W1t, b1, Tt3, agg);
  k_root<<<NBLK_P, 256, 0, stream>>>(x, rootw, conv1b, agg, degI, hpre, rpart);
  k_fold1<<<1, 256, 0, stream>>>(rpart, n1w, n1b, gatw, gw2, tb);
  k_gatlin<<<NBLK_P, 256, 0, stream>>>(hpre, gw2, tb, attS, attD, xh, asrc, adst);
  k_gat<<<NBLK_P, 256, 0, stream>>>(rowptr, colsrc, xh, asrc, adst, gatb, act, gpart);
  k_fold2<<<1, 256, 0, stream>>>(gpart, n2w, n2b, linw, linb, wl);
  k_out<<<NGRAPH, 256, 0, stream>>>(act, wl, batch, (float*)d_out);
}

// Round 12
// 914.323 us; speedup vs baseline: 1.2940x; 1.0592x over previous
//
#include <hip/hip_runtime.h>
#include <hip/hip_bf16.h>

#define N_NODES 50000
#define E_EDGES 300000
#define NGRAPH 64
#define NCHUNK 129
#define CSPLIT 65    // piece 0: c in [0,65), piece 1: [65,129)
#define NKG 1034     // 129*8 kgroups (+2 unused pad)
#define NEGRP 1172   // ceil(E/256)
#define LNEPS 1e-5f
#define NBLK_N 196   // ceil(50000/256)
#define NBLK_P 12500 // N_NODES/4
// prescale so RTZ pack to f16 ~= round-to-nearest
#define RPRE16 1.00048828125f

typedef _Float16 f16x8 __attribute__((ext_vector_type(8)));
typedef _Float16 f16x2 __attribute__((ext_vector_type(2)));
typedef float floatx16 __attribute__((ext_vector_type(16)));
typedef float f32x2 __attribute__((ext_vector_type(2)));
typedef unsigned int u32x4 __attribute__((ext_vector_type(4)));

__device__ __forceinline__ void async_load16(const void* g, void* l) {
  __builtin_amdgcn_global_load_lds(
      (__attribute__((address_space(1))) void*)g,
      (__attribute__((address_space(3))) void*)l, 16, 0, 0);
}

// ---------------- prep: Tt3[kg][half][n][j] f16, coalesced via LDS transpose ----------------
__global__ void k_prep(const float* __restrict__ w2, const float* __restrict__ b2,
                       _Float16* __restrict__ Tt3) {
  __shared__ float tile[32][65];
  int t = threadIdx.x;
  int kg0 = blockIdx.x * 2;       // 2 kg-tiles per block, 517 blocks
  int kf0 = kg0 * 16;
  int kfr = t >> 6;               // 0..3
  int n0 = t & 63;
#pragma unroll
  for (int it = 0; it < 8; ++it) {
    int kfl = it * 4 + kfr;
    int kf = kf0 + kfl;
    float v = 0.f;
    if (kf < 16384) v = w2[(size_t)kf * 64 + n0];
    else if (kf < 16400) v = b2[(size_t)(kf - 16384) * 64 + n0];
    tile[kfl][n0] = v;
  }
  __syncthreads();
  int kgl = t >> 7;               // 0..1
  int half = (t >> 6) & 1;
  int n = t & 63;
  f16x8 pack;
#pragma unroll
  for (int j = 0; j < 8; ++j) pack[j] = (_Float16)tile[kgl * 16 + half * 8 + j][n];
  *(f16x8*)(Tt3 + (size_t)(kg0 + kgl) * 1024 + half * 512 + n * 8) = pack;
}

__global__ void k_prepw(const float* __restrict__ w1, float* __restrict__ W1t) {
  int i = blockIdx.x * 256 + threadIdx.x;
  if (i < 8192) { int k = i >> 3, j = i & 7; W1t[i] = w1[j * 1024 + k]; }
}

// ---------------- CSR build ----------------
__global__ void k_cnt(const int* __restrict__ ei, int* __restrict__ degI) {
  int e = blockIdx.x * 256 + threadIdx.x;
  if (e < E_EDGES) atomicAdd(&degI[ei[E_EDGES + e]], 1);
}

__global__ void k_scanA(const int* __restrict__ degI, int* __restrict__ bsum) {
  __shared__ int sm[256];
  int t = threadIdx.x;
  int i = blockIdx.x * 256 + t;
  sm[t] = (i < N_NODES) ? degI[i] : 0;
  __syncthreads();
  for (int off = 128; off > 0; off >>= 1) {
    if (t < off) sm[t] += sm[t + off];
    __syncthreads();
  }
  if (t == 0) bsum[blockIdx.x] = sm[0];
}

__global__ void k_scanB(const int* __restrict__ bsum, int* __restrict__ bpre) {
  __shared__ int s[256];
  int t = threadIdx.x;
  int v = (t < NBLK_N) ? bsum[t] : 0;
  s[t] = v;
  __syncthreads();
  for (int off = 1; off < 256; off <<= 1) {
    int add = (t >= off) ? s[t - off] : 0;
    __syncthreads();
    s[t] += add;
    __syncthreads();
  }
  if (t < NBLK_N) bpre[t] = s[t] - v;
}

__global__ void k_scanC(const int* __restrict__ degI, const int* __restrict__ bpre,
                        int* __restrict__ rowptr, int* __restrict__ cursor) {
  __shared__ int s[256];
  int t = threadIdx.x;
  int i = blockIdx.x * 256 + t;
  int d = (i < N_NODES) ? degI[i] : 0;
  s[t] = d;
  __syncthreads();
  for (int off = 1; off < 256; off <<= 1) {
    int add = (t >= off) ? s[t - off] : 0;
    __syncthreads();
    s[t] += add;
    __syncthreads();
  }
  int r = bpre[blockIdx.x] + s[t] - d;   // exclusive
  if (i < N_NODES) {
    rowptr[i] = r;
    cursor[i] = r;
    if (i == N_NODES - 1) rowptr[N_NODES] = r + d;
  }
}

__global__ void k_scatter(const int* __restrict__ ei, int* __restrict__ cursor,
                          int* __restrict__ colsrc) {
  int e = blockIdx.x * 256 + threadIdx.x;
  if (e < E_EDGES) {
    int s = ei[e], d = ei[E_EDGES + e];
    int pos = atomicAdd(&cursor[d], 1);
    colsrc[pos] = s;
  }
}

// ---------------- NNConv fused MFMA GEMM, split-K x2, 32x32x16 f16, LDS-shared B ----------------
// R12: all 4 waves of a block consume IDENTICAL B -> stage each chunk ONCE per block into
// LDS (double-buffered, 1 barrier/chunk, 128 MFMA/barrier). L2 B-reads drop 4x (9.7->2.4GB,
// ~280->70us L2 floor). Staging via global_load_lds issued at chunk TOP so the barrier's
// vmcnt(0) drain is covered by the whole MFMA phase (the m97 drain had zero cover).
// Layouts: A[m][k]: m=lane&31, k=(lane>>5)*8+j. B[k][n]: n=lane&31, k=(lane>>5)*8+j.
// C/D: col=lane&31, row=(reg&3)+8*(reg>>2)+4*(lane>>5)  [m74/m101 verified].
__global__ __launch_bounds__(256, 3)
void k_nnconv(const float* __restrict__ x, const int* __restrict__ ei,
              const float* __restrict__ ea, const float* __restrict__ W1t,
              const float* __restrict__ b1, const _Float16* __restrict__ Tt3,
              float* __restrict__ agg) {
  __shared__ __align__(16) _Float16 sB[2][8192];   // 2 x 16KB chunk buffers
  const int tid = threadIdx.x;
  const int wv = tid >> 6;
  const int lane = tid & 63;
  const int l31 = lane & 31;
  const int half = lane >> 5;
  const int grp = blockIdx.x >> 1;
  const int piece = blockIdx.x & 1;
  const int cstart = piece ? CSPLIT : 0;
  const int cend = piece ? NCHUNK : CSPLIT;

  int e = grp * 256 + tid;
  bool valid = e < E_EDGES;
  int srcv = valid ? ei[e] : 0;
  int dstv = valid ? ei[E_EDGES + e] : -1;

  f32x2 ea2[4];
  {
    const float4* p = (const float4*)(ea + (size_t)(valid ? e : 0) * 8);
    float4 a0 = p[0], a1 = p[1];
    ea2[0] = (f32x2){a0.x, a0.y};
    ea2[1] = (f32x2){a0.z, a0.w};
    ea2[2] = (f32x2){a1.x, a1.y};
    ea2[3] = (f32x2){a1.z, a1.w};
  }

  // persistent x fragments: mt in {0,1}, edge m = mt*32+l31, f = half*8 + j
  const int f0 = half * 8;
  unsigned xh16[2][4];
#pragma unroll
  for (int mt = 0; mt < 2; ++mt) {
    int s = __shfl(srcv, mt * 32 + l31);
    const float4* px = (const float4*)(x + (size_t)s * 16 + f0);
    float4 v0 = px[0], v1 = px[1];
    xh16[mt][0] = __builtin_bit_cast(unsigned, __builtin_amdgcn_cvt_pkrtz(v0.x * RPRE16, v0.y * RPRE16));
    xh16[mt][1] = __builtin_bit_cast(unsigned, __builtin_amdgcn_cvt_pkrtz(v0.z * RPRE16, v0.w * RPRE16));
    xh16[mt][2] = __builtin_bit_cast(unsigned, __builtin_amdgcn_cvt_pkrtz(v1.x * RPRE16, v1.y * RPRE16));
    xh16[mt][3] = __builtin_bit_cast(unsigned, __builtin_amdgcn_cvt_pkrtz(v1.z * RPRE16, v1.w * RPRE16));
  }

  // bpermute byte addresses: lane wants r of edge (mt*32 + l31)
  int bpaddr[2];
#pragma unroll
  for (int mt = 0; mt < 2; ++mt) bpaddr[mt] = (mt * 32 + l31) * 4;

  // fragment read offset within a kg tile (elements)
  const int loff = half * 512 + l31 * 8;

  // stage chunk c into sB[nb]: wave wv covers kg tiles {2wv, 2wv+1} (4 x 16B/lane)
  auto stage = [&](int c, int nb) {
    const _Float16* src = Tt3 + ((size_t)c * 8 + 2 * wv) * 1024 + lane * 8;
    _Float16* dst = &sB[nb][2 * wv * 1024 + lane * 8];
    async_load16(src, dst);
    async_load16(src + 512, dst + 512);
    async_load16(src + 1024, dst + 1024);
    async_load16(src + 1536, dst + 1536);
  };

  unsigned prr[4];   // f16-packed r pair: lo16=r[2p], hi16=r[2p+1]
  auto calcR = [&](int c, const float* w1p, const float* b1p) {
    if (c < 128) {   // uniform branch
#pragma unroll
      for (int p = 0; p < 4; ++p) {
        float rv[2];
#pragma unroll
        for (int kk = 0; kk < 2; ++kk) {
          const f32x2* w = (const f32x2*)(w1p + (p * 2 + kk) * 8);  // uniform -> s_load
          f32x2 s01 = ea2[0] * w[0] + ea2[1] * w[1];
          f32x2 s23 = ea2[2] * w[2] + ea2[3] * w[3];
          f32x2 s = s01 + s23;
          rv[kk] = fmaxf(b1p[p * 2 + kk] + s[0] + s[1], 0.f) * RPRE16;
        }
        prr[p] = __builtin_bit_cast(unsigned, __builtin_amdgcn_cvt_pkrtz(rv[0], rv[1]));
      }
    } else {
      prr[0] = 0x00003C00u;  // lo16 = f16(1.0) at k=1024 (b2 rows); rest 0
      prr[1] = prr[2] = prr[3] = 0u;
    }
  };

  unsigned ubuf[8]; // bpermuted r pairs for CURRENT chunk: [pair*2 + mt]
  auto bcastR = [&]() {
#pragma unroll
    for (int p = 0; p < 4; ++p)
#pragma unroll
      for (int mt = 0; mt < 2; ++mt)
        ubuf[p * 2 + mt] = (unsigned)__builtin_amdgcn_ds_bpermute(bpaddr[mt], (int)prr[p]);
  };

  floatx16 acc[2][2];
#pragma unroll
  for (int mt = 0; mt < 2; ++mt)
#pragma unroll
    for (int nt = 0; nt < 2; ++nt)
#pragma unroll
      for (int r = 0; r < 16; ++r) acc[mt][nt][r] = 0.f;

  // prologue
  calcR(cstart, W1t + cstart * 64, b1 + cstart * 8);
  bcastR();
  stage(cstart, 0);
  __syncthreads();   // drains staging vmcnt + barrier
  const float* w1p = W1t + (cstart + 1) * 64;
  const float* b1p = b1 + (cstart + 1) * 8;

  int c = cstart;
  int buf = 0;
  while (true) {
    // 1) extract this chunk's splatted r pairs (frees ubuf for rewrite)
    unsigned rsp[16];
#pragma unroll
    for (int p = 0; p < 4; ++p)
#pragma unroll
      for (int mt = 0; mt < 2; ++mt) {
        unsigned u = ubuf[p * 2 + mt];
        rsp[(2 * p) * 2 + mt]     = __builtin_amdgcn_perm(u, 0u, 0x05040504u); // lo half
        rsp[(2 * p + 1) * 2 + mt] = __builtin_amdgcn_perm(u, 0u, 0x07060706u); // hi half
      }
    // 2) stage chunk c+1 NOW -> vmcnt(0) at the end-of-chunk barrier is fully covered
    bool more = (c + 1 < cend);
    if (more) stage(c + 1, buf ^ 1);
    // 3) next chunk's r pipeline -> covered by MFMA phase below
    if (more) {
      calcR(c + 1, w1p, b1p);
      bcastR();
      w1p += 64; b1p += 8;
    }
    // 4) MFMA phase on sB[buf], 2-slot ds_read rotation
    {
      f16x8 Bs0[2], Bs1[2];
      Bs0[0] = *(const f16x8*)&sB[buf][loff];
      Bs0[1] = *(const f16x8*)&sB[buf][loff + 256];
#pragma unroll
      for (int kg = 0; kg < 8; ++kg) {
        f16x8* cur = (kg & 1) ? Bs1 : Bs0;
        f16x8* nxt = (kg & 1) ? Bs0 : Bs1;
        if (kg < 7) {
          nxt[0] = *(const f16x8*)&sB[buf][(kg + 1) * 1024 + loff];
          nxt[1] = *(const f16x8*)&sB[buf][(kg + 1) * 1024 + loff + 256];
        }
#pragma unroll
        for (int mt = 0; mt < 2; ++mt) {
          f16x2 r2 = __builtin_bit_cast(f16x2, rsp[kg * 2 + mt]);
          u32x4 U;
#pragma unroll
          for (int j = 0; j < 4; ++j)
            U[j] = __builtin_bit_cast(unsigned,
                     __builtin_bit_cast(f16x2, xh16[mt][j]) * r2);
          f16x8 A = __builtin_bit_cast(f16x8, U);
#pragma unroll
          for (int nt = 0; nt < 2; ++nt)
            acc[mt][nt] = __builtin_amdgcn_mfma_f32_32x32x16_f16(A, cur[nt], acc[mt][nt], 0, 0, 0);
        }
      }
    }
    if (!more) break;
    __syncthreads();   // one barrier per chunk: staging (issued at step 2) long arrived
    buf ^= 1;
    ++c;
  }

  // epilogue: scatter partial msg to agg[dst]
  // C layout: col(h-part)=l31, row=(reg&3)+8*(reg>>2)+4*half
#pragma unroll
  for (int mt = 0; mt < 2; ++mt) {
#pragma unroll
    for (int reg = 0; reg < 16; ++reg) {
      int el = mt * 32 + (reg & 3) + 8 * (reg >> 2) + 4 * half;
      int dd = __shfl(dstv, el);
      if (dd >= 0) {
#pragma unroll
        for (int nt = 0; nt < 2; ++nt)
          atomicAdd(&agg[(size_t)dd * 64 + nt * 32 + l31], acc[mt][nt][reg]);
      }
    }
  }
}

// ---------------- h = relu(x@rootw + agg/deg + b); LN1 partials ----------------
__global__ void k_root(const float* __restrict__ x, const float* __restrict__ rootw,
                       const float* __restrict__ conv1b, const float* __restrict__ agg,
                       const int* __restrict__ degI, float* __restrict__ hpre,
                       float* __restrict__ rpart) {
  __shared__ float sW[1024];
  __shared__ float sx[64];
  __shared__ float red[8];
  int t = threadIdx.x;
  int blk = blockIdx.x;
#pragma unroll
  for (int i = 0; i < 4; ++i) sW[t + i * 256] = rootw[t + i * 256];
  if (t < 64) sx[t] = x[(size_t)blk * 64 + t];
  __syncthreads();
  int ln = t >> 6, h = t & 63;
  int n = blk * 4 + ln;
  float acc = conv1b[h];
#pragma unroll
  for (int f = 0; f < 16; ++f) acc += sx[ln * 16 + f] * sW[f * 64 + h];
  float dv = fmaxf((float)degI[n], 1.0f);
  float v = acc + agg[(size_t)n * 64 + h] / dv;
  v = fmaxf(v, 0.f);
  hpre[(size_t)n * 64 + h] = v;
  float s1 = v, s2 = v * v;
  for (int o = 32; o > 0; o >>= 1) { s1 += __shfl_down(s1, o); s2 += __shfl_down(s2, o); }
  if ((t & 63) == 0) { red[t >> 6] = s1; red[4 + (t >> 6)] = s2; }
  __syncthreads();
  if (t == 0) {
    rpart[blk * 2] = red[0] + red[1] + red[2] + red[3];
    rpart[blk * 2 + 1] = red[4] + red[5] + red[6] + red[7];
  }
}

// reduce LN1 partials; fold LN1 into gat_w
__global__ void k_fold1(const float* __restrict__ rpart, const float* __restrict__ n1w,
                        const float* __restrict__ n1b, const float* __restrict__ gatw,
                        float* __restrict__ gw2, float* __restrict__ tb) {
  __shared__ float red[8];
  __shared__ float sMI[2];
  __shared__ float sS[64], sT[64];
  int t = threadIdx.x;
  int wv = t >> 6, lane = t & 63;
  float a = 0.f, b = 0.f;
  for (int i = t; i < NBLK_P; i += 256) { a += rpart[2 * i]; b += rpart[2 * i + 1]; }
  for (int o = 32; o > 0; o >>= 1) { a += __shfl_down(a, o); b += __shfl_down(b, o); }
  if (lane == 0) { red[wv] = a; red[4 + wv] = b; }
  __syncthreads();
  if (t == 0) {
    float A = red[0] + red[1] + red[2] + red[3];
    float B = red[4] + red[5] + red[6] + red[7];
    const float M = (float)N_NODES * 64.f;
    float mu = A / M;
    float var = fmaxf(B / M - mu * mu, 0.f);
    sMI[0] = mu;
    sMI[1] = 1.f / (sqrtf(var) + LNEPS);
  }
  __syncthreads();
  if (t < 64) {
    float mu = sMI[0], inv = sMI[1];
    sS[t] = inv * n1w[t];
    sT[t] = n1b[t] - mu * inv * n1w[t];
  }
  __syncthreads();
  if (t < 64) {
    float acc = 0.f;
    for (int i = 0; i < 64; ++i) {
      float g = gatw[i * 64 + t];
      gw2[i * 64 + t] = sS[i] * g;
      acc += sT[i] * g;
    }
    tb[t] = acc;
  }
}

// xh = hpre@gw2 + tb ; attention scalars
__global__ void k_gatlin(const float* __restrict__ hpre, const float* __restrict__ gw2,
                         const float* __restrict__ tb, const float* __restrict__ attS,
                         const float* __restrict__ attD, float* __restrict__ xh,
                         float* __restrict__ asrc, float* __restrict__ adst) {
  __shared__ float sW[4096];
  __shared__ float sh[256];
  __shared__ float sxh[256];
  int t = threadIdx.x;
  int blk = blockIdx.x;
#pragma unroll
  for (int i = 0; i < 16; ++i) sW[t + i * 256] = gw2[t + i * 256];
  sh[t] = hpre[(size_t)blk * 256 + t];
  __syncthreads();
  int ln = t >> 6, h = t & 63;
  float acc = tb[h];
  for (int i = 0; i < 64; ++i) acc += sh[ln * 64 + i] * sW[i * 64 + h];
  xh[(size_t)blk * 256 + t] = acc;
  sxh[t] = acc;
  __syncthreads();
  if (t < 32) {
    int ln2 = t >> 3, rem = t & 7;
    int hd = rem & 3;
    const float* av = (rem >> 2) ? attD : attS;
    float a = 0.f;
#pragma unroll
    for (int d = 0; d < 16; ++d) a += sxh[ln2 * 64 + hd * 16 + d] * av[hd * 16 + d];
    int n = blk * 4 + ln2;
    if (rem >> 2) adst[n * 4 + hd] = a; else asrc[n * 4 + hd] = a;
  }
}

// ---------------- GAT: CSR gather, online softmax, fused relu + LN2 partials ----------------
__global__ void k_gat(const int* __restrict__ rowptr, const int* __restrict__ colsrc,
                      const float* __restrict__ xh, const float* __restrict__ asrc,
                      const float* __restrict__ adst, const float* __restrict__ gatb,
                      float* __restrict__ act, float* __restrict__ gpart) {
  __shared__ float sP[4][256];
  __shared__ int sS[4][64];
  __shared__ float sRed[8];
  int t = threadIdx.x;
  int wv = t >> 6, lane = t & 63;
  int n = blockIdx.x * 4 + wv;
  int start = rowptr[n], end = rowptr[n + 1];
  int deg = end - start;
  int myhd = lane >> 4;
  float ad[4];
#pragma unroll
  for (int hd = 0; hd < 4; ++hd) ad[hd] = adst[n * 4 + hd];
  float m[4] = {-1e30f, -1e30f, -1e30f, -1e30f};
  float l[4] = {0.f, 0.f, 0.f, 0.f};
  float O = 0.f;
  int items = deg + 1;  // + self loop
  for (int t0 = 0; t0 < items; t0 += 64) {
    int cnt = min(64, items - t0);
    int idx = t0 + lane;
    bool has = lane < cnt;
    int s = n;
    if (has && idx < deg) s = colsrc[start + idx];
    float a[4];
#pragma unroll
    for (int hd = 0; hd < 4; ++hd) {
      float av = has ? (asrc[s * 4 + hd] + ad[hd]) : -1e30f;
      a[hd] = (av > 0.f) ? av : 0.2f * av;  // leaky relu 0.2
    }
    float tm[4];
#pragma unroll
    for (int hd = 0; hd < 4; ++hd) tm[hd] = a[hd];
#pragma unroll
    for (int off = 32; off > 0; off >>= 1)
#pragma unroll
      for (int hd = 0; hd < 4; ++hd) tm[hd] = fmaxf(tm[hd], __shfl_xor(tm[hd], off));
    float p[4];
#pragma unroll
    for (int hd = 0; hd < 4; ++hd) {
      float mn = fmaxf(m[hd], tm[hd]);
      float sc = __expf(m[hd] - mn);
      l[hd] *= sc;
      if (hd == myhd) O *= sc;
      m[hd] = mn;
      p[hd] = has ? __expf(a[hd] - mn) : 0.f;
    }
    float ts[4];
#pragma unroll
    for (int hd = 0; hd < 4; ++hd) ts[hd] = p[hd];
#pragma unroll
    for (int off = 32; off > 0; off >>= 1)
#pragma unroll
      for (int hd = 0; hd < 4; ++hd) ts[hd] += __shfl_xor(ts[hd], off);
#pragma unroll
    for (int hd = 0; hd < 4; ++hd) l[hd] += ts[hd];
    sS[wv][lane] = s;
#pragma unroll
    for (int hd = 0; hd < 4; ++hd) sP[wv][lane * 4 + hd] = p[hd];
    // wave-private LDS region: program order suffices, no barrier
    for (int e2 = 0; e2 < cnt; ++e2) {
      int ss = sS[wv][e2];
      float pp = sP[wv][e2 * 4 + myhd];
      O = fmaf(pp, xh[(size_t)ss * 64 + lane], O);
    }
  }
  float lmy = (myhd & 2) ? ((myhd & 1) ? l[3] : l[2]) : ((myhd & 1) ? l[1] : l[0]);
  float outv = O / (lmy + 1e-16f);
  float v = fmaxf(outv + gatb[lane], 0.f);
  act[(size_t)n * 64 + lane] = v;
  float s1 = v, s2 = v * v;
#pragma unroll
  for (int off = 32; off > 0; off >>= 1) { s1 += __shfl_down(s1, off); s2 += __shfl_down(s2, off); }
  if (lane == 0) { sRed[wv] = s1; sRed[4 + wv] = s2; }
  __syncthreads();
  if (t == 0) {
    gpart[blockIdx.x * 2] = sRed[0] + sRed[1] + sRed[2] + sRed[3];
    gpart[blockIdx.x * 2 + 1] = sRed[4] + sRed[5] + sRed[6] + sRed[7];
  }
}

// reduce LN2 partials; fold LN2 + linear head into wl
__global__ void k_fold2(const float* __restrict__ gpart, const float* __restrict__ n2w,
                        const float* __restrict__ n2b, const float* __restrict__ linw,
                        const float* __restrict__ linb, float* __restrict__ wl) {
  __shared__ float red[8];
  __shared__ float sMI[2];
  int t = threadIdx.x;
  int wv = t >> 6, lane = t & 63;
  float a = 0.f, b = 0.f;
  for (int i = t; i < NBLK_P; i += 256) { a += gpart[2 * i]; b += gpart[2 * i + 1]; }
  for (int o = 32; o > 0; o >>= 1) { a += __shfl_down(a, o); b += __shfl_down(b, o); }
  if (lane == 0) { red[wv] = a; red[4 + wv] = b; }
  __syncthreads();
  if (t == 0) {
    float A = red[0] + red[1] + red[2] + red[3];
    float B = red[4] + red[5] + red[6] + red[7];
    const float M = (float)N_NODES * 64.f;
    float mu = A / M;
    float var = fmaxf(B / M - mu * mu, 0.f);
    sMI[0] = mu;
    sMI[1] = 1.f / (sqrtf(var) + LNEPS);
  }
  __syncthreads();
  if (t < 64) {
    float mu = sMI[0], inv = sMI[1];
    float w = inv * n2w[t] * linw[t];
    float p = (n2b[t] - mu * inv * n2w[t]) * linw[t];
    wl[t] = w;
    for (int o = 32; o > 0; o >>= 1) p += __shfl_down(p, o);
    if (t == 0) wl[64] = p + linb[0];
  }
}

// per-graph segmented pool + head (batch is sorted; zero atomics)
__global__ void k_out(const float* __restrict__ act, const float* __restrict__ wl,
                      const int* __restrict__ batch, float* __restrict__ out) {
  __shared__ float red[4];
  __shared__ float swl[64];
  int g = blockIdx.x;
  int t = threadIdx.x;
  int wv = t >> 6, lane = t & 63;
  if (t < 64) swl[t] = wl[t];
  __syncthreads();
  auto lbound = [&](int key) {
    int lo = 0, hi = N_NODES;
    while (lo < hi) { int mid = (lo + hi) >> 1; if (batch[mid] < key) lo = mid + 1; else hi = mid; }
    return lo;
  };
  int lo = lbound(g), hi = lbound(g + 1);
  int cntn = hi - lo;
  float s = 0.f;
  for (int idx = t; idx < cntn * 64; idx += 256) {
    int n = lo + (idx >> 6);
    int d = idx & 63;
    s += act[(size_t)n * 64 + d] * swl[d];
  }
  for (int o = 32; o > 0; o >>= 1) s += __shfl_down(s, o);
  if (lane == 0) red[wv] = s;
  __syncthreads();
  if (t == 0)
    out[g] = (red[0] + red[1] + red[2] + red[3]) / fmaxf((float)cntn, 1.f) + wl[64];
}

// ---------------- workspace layout (bytes, 64B aligned) ----------------
#define OFF_AGG     0UL
#define OFF_DEGI    12800000UL
#define ZBYTES      13000000UL
#define OFF_RPART   13000000UL
#define OFF_GPART   13100032UL
#define OFF_ROWPTR  13200064UL
#define OFF_CURSOR  13400128UL
#define OFF_BSUM    13600192UL
#define OFF_BPRE    13601024UL
#define OFF_COLSRC  13601856UL
#define OFF_TT      14801856UL   // NKG*1024*2 = 2117632
#define OFF_W1T     16923584UL
#define OFF_GW2     16956352UL
#define OFF_TB      16972736UL
#define OFF_WL      16972992UL
#define OFF_ASRC    16973312UL
#define OFF_ADST    17773312UL
#define OFF_HPRE    18573312UL
#define OFF_XH      31373312UL
#define OFF_ACT     44173312UL
#define WS_NEED     56973312UL

extern "C" void kernel_launch(void* const* d_in, const int* in_sizes, int n_in,
                              void* d_out, int out_size, void* d_ws, size_t ws_size,
                              hipStream_t stream) {
  const float* x = (const float*)d_in[0];
  const int* ei = (const int*)d_in[1];
  const float* ea = (const float*)d_in[2];
  const int* batch = (const int*)d_in[3];
  const float* w1 = (const float*)d_in[4];
  const float* b1 = (const float*)d_in[5];
  const float* w2 = (const float*)d_in[6];
  const float* b2 = (const float*)d_in[7];
  const float* rootw = (const float*)d_in[8];
  const float* conv1b = (const float*)d_in[9];
  const float* n1w = (const float*)d_in[10];
  const float* n1b = (const float*)d_in[11];
  const float* gatw = (const float*)d_in[12];
  const float* attS = (const float*)d_in[13];
  const float* attD = (const float*)d_in[14];
  const float* gatb = (const float*)d_in[15];
  const float* n2w = (const float*)d_in[16];
  const float* n2b = (const float*)d_in[17];
  const float* linw = (const float*)d_in[18];
  const float* linb = (const float*)d_in[19];

  if (ws_size < WS_NEED) return;
  char* ws = (char*)d_ws;
  float* agg    = (float*)(ws + OFF_AGG);
  int* degI     = (int*)(ws + OFF_DEGI);
  float* rpart  = (float*)(ws + OFF_RPART);
  float* gpart  = (float*)(ws + OFF_GPART);
  int* rowptr   = (int*)(ws + OFF_ROWPTR);
  int* cursor   = (int*)(ws + OFF_CURSOR);
  int* bsum     = (int*)(ws + OFF_BSUM);
  int* bpre     = (int*)(ws + OFF_BPRE);
  int* colsrc   = (int*)(ws + OFF_COLSRC);
  _Float16* Tt3 = (_Float16*)(ws + OFF_TT);
  float* W1t    = (float*)(ws + OFF_W1T);
  float* gw2    = (float*)(ws + OFF_GW2);
  float* tb     = (float*)(ws + OFF_TB);
  float* wl     = (float*)(ws + OFF_WL);
  float* asrc   = (float*)(ws + OFF_ASRC);
  float* adst   = (float*)(ws + OFF_ADST);
  float* hpre   = (float*)(ws + OFF_HPRE);
  float* xh     = (float*)(ws + OFF_XH);
  float* act    = (float*)(ws + OFF_ACT);

  hipMemsetAsync(ws, 0, ZBYTES, stream);

  k_prep<<<(NKG + 1) / 2, 256, 0, stream>>>(w2, b2, Tt3);
  k_prepw<<<32, 256, 0, stream>>>(w1, W1t);
  k_cnt<<<(E_EDGES + 255) / 256, 256, 0, stream>>>(ei, degI);
  k_scanA<<<NBLK_N, 256, 0, stream>>>(degI, bsum);
  k_scanB<<<1, 256, 0, stream>>>(bsum, bpre);
  k_scanC<<<NBLK_N, 256, 0, stream>>>(degI, bpre, rowptr, cursor);
  k_scatter<<<(E_EDGES + 255) / 256, 256, 0, stream>>>(ei, cursor, colsrc);
  k_nnconv<<<NEGRP * 2, 256, 0, stream>>>(x, ei, ea, W1t, b1, Tt3, agg);
  k_root<<<NBLK_P, 256, 0, stream>>>(x, rootw, conv1b, agg, degI, hpre, rpart);
  k_fold1<<<1, 256, 0, stream>>>(rpart, n1w, n1b, gatw, gw2, tb);
  k_gatlin<<<NBLK_P, 256, 0, stream>>>(hpre, gw2, tb, attS, attD, xh, asrc, adst);
  k_gat<<<NBLK_P, 256, 0, stream>>>(rowptr, colsrc, xh, asrc, adst, gatb, act, gpart);
  k_fold2<<<1, 256, 0, stream>>>(gpart, n2w, n2b, linw, linb, wl);
  k_out<<<NGRAPH, 256, 0, stream>>>(act, wl, batch, (float*)d_out);
}